// Round 6
// baseline (609.053 us; speedup 1.0000x reference)
//
#include <hip/hip_runtime.h>
#include <hip/hip_fp16.h>
#include <math.h>

#define N_NODES 50000
#define N_EDGES 800000
#define E_TOT   (N_EDGES + N_NODES)   // 850000, self-loops appended
#define IN_DIM  32
#define HID     96
#define NEG_SLOPE 0.2f
#define MAXD    256                   // LDS chunk per wave (alpha kernel)
#define SCAN_BS 1024
#define N_SCAN_BLOCKS ((N_NODES + SCAN_BS - 1) / SCAN_BS)   // 49
#define FILL_PASSES 8
#define FILL_WIN (N_NODES / FILL_PASSES)   // 6250
#define NODE_BLOCKS (N_NODES / 4)          // 12500 blocks of 4 waves/nodes

static inline int cdiv(long long a, int b) { return (int)((a + b - 1) / b); }

// ---------------- CSR build (counting sort by dst), once per launch ----------------

__global__ void hist_kernel(const int* __restrict__ ei, unsigned* __restrict__ deg) {
    int e = blockIdx.x * blockDim.x + threadIdx.x;
    if (e >= E_TOT) return;
    int d = (e < N_EDGES) ? ei[N_EDGES + e] : (e - N_EDGES);
    atomicAdd(deg + d, 1u);
}

__global__ void scan_block_kernel(const unsigned* __restrict__ deg, unsigned* __restrict__ rs,
                                  unsigned* __restrict__ bsums, int n) {
    __shared__ unsigned buf[SCAN_BS];
    int i = blockIdx.x * SCAN_BS + threadIdx.x;
    unsigned v = (i < n) ? deg[i] : 0u;
    buf[threadIdx.x] = v;
    __syncthreads();
    for (int o = 1; o < SCAN_BS; o <<= 1) {
        unsigned t = (threadIdx.x >= (unsigned)o) ? buf[threadIdx.x - o] : 0u;
        __syncthreads();
        buf[threadIdx.x] += t;
        __syncthreads();
    }
    if (i < n) rs[i] = buf[threadIdx.x] - v;
    if (threadIdx.x == SCAN_BS - 1) bsums[blockIdx.x] = buf[SCAN_BS - 1];
}

// scan_fix with the (<=49-entry) block-sum prefix computed in-block by wave 0
__global__ void scan_fix_kernel(unsigned* __restrict__ rs, const unsigned* __restrict__ bsums,
                                unsigned* __restrict__ wptr, int n) {
    __shared__ unsigned s_off;
    int k = blockIdx.x >> 2;
    if (threadIdx.x < 64) {
        unsigned v = ((int)threadIdx.x < k) ? bsums[threadIdx.x] : 0u;
        #pragma unroll
        for (int o = 32; o; o >>= 1) v += __shfl_xor(v, o);
        if (threadIdx.x == 0) s_off = v;
    }
    __syncthreads();
    unsigned off = s_off;
    int i = blockIdx.x * 256 + threadIdx.x;
    if (i < n) {
        unsigned r = rs[i] + off;
        rs[i] = r;
        wptr[i] = r;
    }
    if (i == n) rs[n] = E_TOT;
}

// Windowed fill: pass p only materializes dst in [p*WIN,(p+1)*WIN) -> localized writes.
__global__ void fill_win_kernel(const int* __restrict__ ei, unsigned* __restrict__ wptr,
                                int* __restrict__ srcs) {
    const int nb_e = (E_TOT + 255) / 256;
    int pass = blockIdx.x / nb_e;
    int eb   = blockIdx.x - pass * nb_e;
    int e = eb * 256 + threadIdx.x;
    if (e >= E_TOT) return;
    int lo = pass * FILL_WIN;
    int d = (e < N_EDGES) ? ei[N_EDGES + e] : (e - N_EDGES);
    if ((unsigned)(d - lo) >= (unsigned)FILL_WIN) return;
    int s = (e < N_EDGES) ? ei[e] : d;
    unsigned pos = atomicAdd(wptr + d, 1u);
    srcs[pos] = s;
}

// ---------------- GEMM: 4-node x 4-channel micro-tile, fp16 PLANE output ----------------
// h layout: 3 planes of 32 channels: H2[(plane*N + node)*16 + ch2]  (half2 units)

__device__ __forceinline__ void fma4(float4& a, float s, const float4& w) {
    a.x += s * w.x; a.y += s * w.y; a.z += s * w.z; a.w += s * w.w;
}

__global__ void gemm_h16_kernel(const float* __restrict__ x, const float* __restrict__ W,
                                __half* __restrict__ h, int n, int din) {
    int idx = blockIdx.x * blockDim.x + threadIdx.x;   // (n/4)*24 threads
    int ngroups = n >> 2;
    if (idx >= ngroups * 24) return;
    int g   = idx / 24;
    int c4q = idx - g * 24;          // float4 column index (channels c4q*4 .. +3)
    int n0 = g * 4;
    int k4n = din >> 2;
    const float4* X4 = (const float4*)x;
    const float4* W4 = (const float4*)W;   // row stride 24 float4
    const float4* Xa = X4 + (size_t)n0 * k4n;
    const float4* Xb = Xa + k4n;
    const float4* Xc = Xb + k4n;
    const float4* Xd = Xc + k4n;

    float4 accA = {0,0,0,0}, accB = {0,0,0,0}, accC = {0,0,0,0}, accD = {0,0,0,0};
    for (int k4 = 0; k4 < k4n; ++k4) {
        float4 xa = Xa[k4], xb = Xb[k4], xc = Xc[k4], xd = Xd[k4];
        #pragma unroll
        for (int kk = 0; kk < 4; ++kk) {
            float4 w = W4[(size_t)(k4 * 4 + kk) * 24 + c4q];
            fma4(accA, ((const float*)&xa)[kk], w);
            fma4(accB, ((const float*)&xb)[kk], w);
            fma4(accC, ((const float*)&xc)[kk], w);
            fma4(accD, ((const float*)&xd)[kk], w);
        }
    }
    int plane = c4q >> 3;            // 0..2
    int q     = c4q & 7;             // float4 within plane
    __half2* H2 = (__half2*)h;
    size_t rb = ((size_t)plane * N_NODES + n0) * 16 + q * 2;
    {
        __half2 p0 = __floats2half2_rn(accA.x, accA.y), p1 = __floats2half2_rn(accA.z, accA.w);
        uint2 st; st.x = *(unsigned*)&p0; st.y = *(unsigned*)&p1;
        *(uint2*)(H2 + rb) = st;
    }
    {
        __half2 p0 = __floats2half2_rn(accB.x, accB.y), p1 = __floats2half2_rn(accB.z, accB.w);
        uint2 st; st.x = *(unsigned*)&p0; st.y = *(unsigned*)&p1;
        *(uint2*)(H2 + rb + 16) = st;
    }
    {
        __half2 p0 = __floats2half2_rn(accC.x, accC.y), p1 = __floats2half2_rn(accC.z, accC.w);
        uint2 st; st.x = *(unsigned*)&p0; st.y = *(unsigned*)&p1;
        *(uint2*)(H2 + rb + 32) = st;
    }
    {
        __half2 p0 = __floats2half2_rn(accD.x, accD.y), p1 = __floats2half2_rn(accD.z, accD.w);
        uint2 st; st.x = *(unsigned*)&p0; st.y = *(unsigned*)&p1;
        *(uint2*)(H2 + rb + 48) = st;
    }
}

// es/ed from plane-layout fp16 h. lane<48: plane=lane>>4, c=lane&15; channels 32p+2c == 2*lane.
__global__ void scores_kernel(const __half* __restrict__ h, const float* __restrict__ a_s,
                              const float* __restrict__ a_d, float* __restrict__ es,
                              float* __restrict__ ed, int n) {
    int node = (int)((blockIdx.x * (long long)blockDim.x + threadIdx.x) >> 6);
    int lane = threadIdx.x & 63;
    if (node >= n) return;
    float ps = 0.f, pd = 0.f;
    if (lane < 48) {
        int plane = lane >> 4, c = lane & 15;
        const __half2* h2 = (const __half2*)h;
        float2 hv = __half22float2(h2[((size_t)plane * N_NODES + node) * 16 + c]);
        float2 sv = ((const float2*)a_s)[lane];
        float2 dv = ((const float2*)a_d)[lane];
        ps = hv.x * sv.x + hv.y * sv.y;
        pd = hv.x * dv.x + hv.y * dv.y;
    }
    #pragma unroll
    for (int o = 32; o; o >>= 1) {
        ps += __shfl_xor(ps, o);
        pd += __shfl_xor(pd, o);
    }
    if (lane == 0) { es[node] = ps; ed[node] = pd; }
}

__global__ void final_proj_kernel(const float* __restrict__ x, const float* __restrict__ Wf,
                                  const float* __restrict__ asf, const float* __restrict__ adf,
                                  float* __restrict__ h, float* __restrict__ es,
                                  float* __restrict__ ed, int n) {
    int node = (int)((blockIdx.x * (long long)blockDim.x + threadIdx.x) >> 6);
    int lane = threadIdx.x & 63;
    if (node >= n) return;
    const float* xr = x + (long long)node * HID;
    float p = 0.f;
    for (int c = lane; c < HID; c += 64) p += xr[c] * Wf[c];
    #pragma unroll
    for (int o = 32; o; o >>= 1) p += __shfl_xor(p, o);
    if (lane == 0) {
        h[node] = p;
        es[node] = p * asf[0];
        ed[node] = p * adf[0];
    }
}

// ---------------- alpha: per-edge normalized softmax weight, packed (src, alpha) ----------------
// One wave per node: max -> exp -> sum -> write EV2[row+j] = {src, alpha}.
__global__ __launch_bounds__(256) void alpha_kernel(
    const unsigned* __restrict__ rs, const int* __restrict__ srcs,
    const float* __restrict__ es, const float* __restrict__ ed,
    uint2* __restrict__ ev2) {
    __shared__ uint2 sh[4][MAXD];
    int node = (int)((blockIdx.x * (long long)blockDim.x + threadIdx.x) >> 6);
    int lane = threadIdx.x & 63;
    int wv = threadIdx.x >> 6;
    if (node >= N_NODES) return;
    unsigned row = rs[node];
    int deg = (int)(rs[node + 1] - row);
    float edv = ed[node];
    bool single = (deg <= MAXD);

    float lmax = -1e30f;
    for (int j = lane; j < deg; j += 64) {
        int s = srcs[row + j];
        float v = es[s] + edv;
        v = v > 0.f ? v : NEG_SLOPE * v;
        if (single) { uint2 p; p.x = (unsigned)s; p.y = __float_as_uint(v); sh[wv][j] = p; }
        lmax = fmaxf(lmax, v);
    }
    #pragma unroll
    for (int o = 32; o; o >>= 1) lmax = fmaxf(lmax, __shfl_xor(lmax, o));

    float lsum = 0.f;
    if (single) {
        for (int j = lane; j < deg; j += 64) {
            uint2 p = sh[wv][j];
            float ex = __expf(__uint_as_float(p.y) - lmax);
            p.y = __float_as_uint(ex);
            sh[wv][j] = p;
            lsum += ex;
        }
    } else {
        for (int j = lane; j < deg; j += 64) {
            int s = srcs[row + j];
            float v = es[s] + edv;
            v = v > 0.f ? v : NEG_SLOPE * v;
            lsum += __expf(v - lmax);
        }
    }
    #pragma unroll
    for (int o = 32; o; o >>= 1) lsum += __shfl_xor(lsum, o);
    float inv = 1.f / lsum;

    if (single) {
        for (int j = lane; j < deg; j += 64) {
            uint2 p = sh[wv][j];
            p.y = __float_as_uint(__uint_as_float(p.y) * inv);
            ev2[row + j] = p;
        }
    } else {
        for (int j = lane; j < deg; j += 64) {
            int s = srcs[row + j];
            float v = es[s] + edv;
            v = v > 0.f ? v : NEG_SLOPE * v;
            uint2 p; p.x = (unsigned)s; p.y = __float_as_uint(__expf(v - lmax) * inv);
            ev2[row + j] = p;
        }
    }
}

// ---------------- plane-major gather: out[n, 32ch of plane] = sum alpha * h_plane[src] ----------
// grid = 3 * NODE_BLOCKS; blocks 0..12499 plane 0, etc. -> co-resident blocks share one
// 3.2 MB plane (L2-resident). 16 lanes x 4 rows per load; xor(16)/xor(32) cross-group reduce.
__global__ __launch_bounds__(256) void gather96_kernel(
    const unsigned* __restrict__ rs, const uint2* __restrict__ ev2,
    const __half* __restrict__ h, const float* __restrict__ b,
    const float* __restrict__ res, float* __restrict__ out, int do_relu) {
    int plane = blockIdx.x / NODE_BLOCKS;
    int nb    = blockIdx.x - plane * NODE_BLOCKS;
    int node  = nb * 4 + (threadIdx.x >> 6);
    int lane  = threadIdx.x & 63;
    int g = lane >> 4, c = lane & 15;
    unsigned row = rs[node];
    int deg = (int)(rs[node + 1] - row);
    const __half2* hp = (const __half2*)h + (size_t)plane * N_NODES * 16;

    float ax = 0.f, ay = 0.f;
    #pragma unroll 2
    for (int jb = 0; jb < deg; jb += 4) {
        int r = jb + g;
        if (r < deg) {
            uint2 p = ev2[row + r];
            float a = __uint_as_float(p.y);
            float2 v = __half22float2(hp[(size_t)p.x * 16 + c]);
            ax += a * v.x;
            ay += a * v.y;
        }
    }
    ax += __shfl_xor(ax, 16); ay += __shfl_xor(ay, 16);
    ax += __shfl_xor(ax, 32); ay += __shfl_xor(ay, 32);

    if (g == 0) {
        int ch2 = plane * 16 + c;    // float2 index within the 96-ch row
        float2 bb = ((const float2*)b)[ch2];
        float vx = ax + bb.x, vy = ay + bb.y;
        if (res) {
            float2 rr = ((const float2*)res)[(size_t)node * 48 + ch2];
            vx += rr.x; vy += rr.y;
        }
        if (do_relu) { vx = fmaxf(vx, 0.f); vy = fmaxf(vy, 0.f); }
        float2 o2; o2.x = vx; o2.y = vy;
        ((float2*)out)[(size_t)node * 48 + ch2] = o2;
    }
}

// ---------------- dout=1 aggregate (final layer, fp32 scalar h) ----------------
__global__ __launch_bounds__(256) void aggregate1_kernel(
    const unsigned* __restrict__ rs, const int* __restrict__ srcs,
    const float* __restrict__ es, const float* __restrict__ ed,
    const float* __restrict__ h, const float* __restrict__ b,
    float* __restrict__ out) {
    int node = (int)((blockIdx.x * (long long)blockDim.x + threadIdx.x) >> 6);
    int lane = threadIdx.x & 63;
    if (node >= N_NODES) return;
    unsigned row = rs[node];
    int deg = (int)(rs[node + 1] - row);
    float edv = ed[node];

    float lmax = -1e30f;
    for (int j = lane; j < deg; j += 64) {
        int s = srcs[row + j];
        float v = es[s] + edv;
        v = v > 0.f ? v : NEG_SLOPE * v;
        lmax = fmaxf(lmax, v);
    }
    #pragma unroll
    for (int o = 32; o; o >>= 1) lmax = fmaxf(lmax, __shfl_xor(lmax, o));

    float lsum = 0.f, acc = 0.f;
    for (int j = lane; j < deg; j += 64) {
        int s = srcs[row + j];
        float v = es[s] + edv;
        v = v > 0.f ? v : NEG_SLOPE * v;
        float ex = __expf(v - lmax);
        lsum += ex;
        acc += ex * h[s];
    }
    #pragma unroll
    for (int o = 32; o; o >>= 1) {
        lsum += __shfl_xor(lsum, o);
        acc  += __shfl_xor(acc, o);
    }
    if (lane == 0) out[node] = acc / lsum + b[0];
}

// ---------------- host-side orchestration ----------------

extern "C" void kernel_launch(void* const* d_in, const int* in_sizes, int n_in,
                              void* d_out, int out_size, void* d_ws, size_t ws_size,
                              hipStream_t stream) {
    const float* x  = (const float*)d_in[0];
    const int*   ei = (const int*)d_in[1];
    const float* W0 = (const float*)d_in[3];
    const float* as0 = (const float*)d_in[4];
    const float* ad0 = (const float*)d_in[5];
    const float* b0 = (const float*)d_in[6];
    const float* W1 = (const float*)d_in[7];
    const float* as1 = (const float*)d_in[8];
    const float* ad1 = (const float*)d_in[9];
    const float* b1 = (const float*)d_in[10];
    const float* W2 = (const float*)d_in[11];
    const float* as2 = (const float*)d_in[12];
    const float* ad2 = (const float*)d_in[13];
    const float* b2 = (const float*)d_in[14];
    const float* Wf = (const float*)d_in[15];
    const float* asf = (const float*)d_in[16];
    const float* adf = (const float*)d_in[17];
    const float* bf = (const float*)d_in[18];

    float* out = (float*)d_out;  // 50000 floats

    // workspace carve-up
    float* Hf = (float*)d_ws;                    // N*96 floats slot (fp16 planes / final fp32 h)
    __half* H16 = (__half*)Hf;
    float* FA = Hf + (long long)N_NODES * HID;   // N*96
    float* FB = FA + (long long)N_NODES * HID;   // N*96
    float* ES = FB + (long long)N_NODES * HID;   // N
    float* ED = ES + N_NODES;                    // N
    unsigned* RS   = (unsigned*)(ED + N_NODES);  // N+1
    unsigned* WPTR = RS + (N_NODES + 1);         // N
    int* SRCS = (int*)(WPTR + N_NODES);          // E_TOT
    uint2* EV2 = (uint2*)(SRCS + E_TOT + 2);     // E_TOT uint2 (8B-aligned: offset even)
    unsigned* DEG = (unsigned*)Hf;               // CSR temporaries aliased onto H slot
    unsigned* BS  = DEG + N_NODES;

    // ---- CSR build ----
    hipMemsetAsync(DEG, 0, (size_t)N_NODES * sizeof(unsigned), stream);
    hist_kernel<<<cdiv(E_TOT, 256), 256, 0, stream>>>(ei, DEG);
    scan_block_kernel<<<N_SCAN_BLOCKS, SCAN_BS, 0, stream>>>(DEG, RS, BS, N_NODES);
    scan_fix_kernel<<<cdiv(N_NODES + 1, 256), 256, 0, stream>>>(RS, BS, WPTR, N_NODES);
    {
        const int nb_e = cdiv(E_TOT, 256);
        fill_win_kernel<<<nb_e * FILL_PASSES, 256, 0, stream>>>(ei, WPTR, SRCS);
    }

    const int gemm_threads = (N_NODES / 4) * 24;   // 300000

    // ---- layer 0: x(32) -> FA(96), relu, no residual ----
    gemm_h16_kernel<<<cdiv(gemm_threads, 256), 256, 0, stream>>>(x, W0, H16, N_NODES, IN_DIM);
    scores_kernel<<<NODE_BLOCKS, 256, 0, stream>>>(H16, as0, ad0, ES, ED, N_NODES);
    alpha_kernel<<<NODE_BLOCKS, 256, 0, stream>>>(RS, SRCS, ES, ED, EV2);
    gather96_kernel<<<3 * NODE_BLOCKS, 256, 0, stream>>>(RS, EV2, H16, b0, nullptr, FA, 1);

    // ---- layer 1: FA -> FB, residual FA, relu ----
    gemm_h16_kernel<<<cdiv(gemm_threads, 256), 256, 0, stream>>>(FA, W1, H16, N_NODES, HID);
    scores_kernel<<<NODE_BLOCKS, 256, 0, stream>>>(H16, as1, ad1, ES, ED, N_NODES);
    alpha_kernel<<<NODE_BLOCKS, 256, 0, stream>>>(RS, SRCS, ES, ED, EV2);
    gather96_kernel<<<3 * NODE_BLOCKS, 256, 0, stream>>>(RS, EV2, H16, b1, FA, FB, 1);

    // ---- layer 2: FB -> FA, residual FB, relu ----
    gemm_h16_kernel<<<cdiv(gemm_threads, 256), 256, 0, stream>>>(FB, W2, H16, N_NODES, HID);
    scores_kernel<<<NODE_BLOCKS, 256, 0, stream>>>(H16, as2, ad2, ES, ED, N_NODES);
    alpha_kernel<<<NODE_BLOCKS, 256, 0, stream>>>(RS, SRCS, ES, ED, EV2);
    gather96_kernel<<<3 * NODE_BLOCKS, 256, 0, stream>>>(RS, EV2, H16, b2, FB, FA, 1);

    // ---- final: FA -> out (dout=1), fp32 path ----
    final_proj_kernel<<<NODE_BLOCKS, 256, 0, stream>>>(FA, Wf, asf, adf, Hf, ES, ED, N_NODES);
    aggregate1_kernel<<<NODE_BLOCKS, 256, 0, stream>>>(RS, SRCS, ES, ED, Hf, bf, out);
}

// Round 7
// 416.643 us; speedup vs baseline: 1.4618x; 1.4618x over previous
//
#include <hip/hip_runtime.h>
#include <hip/hip_fp16.h>
#include <math.h>

#define N_NODES 50000
#define N_EDGES 800000
#define E_TOT   (N_EDGES + N_NODES)   // 850000, self-loops appended
#define IN_DIM  32
#define HID     96
#define NEG_SLOPE 0.2f
#define MAXD    128                   // LDS chunk per wave (per-chunk staging)
#define SCAN_BS 1024
#define N_SCAN_BLOCKS ((N_NODES + SCAN_BS - 1) / SCAN_BS)   // 49
#define FILL_PASSES 8
#define FILL_WIN (N_NODES / FILL_PASSES)   // 6250
#define NODE_BLOCKS (N_NODES / 4)          // 12500 blocks of 4 waves/nodes

static inline int cdiv(long long a, int b) { return (int)((a + b - 1) / b); }

// ---------------- CSR build (counting sort by dst), once per launch ----------------

__global__ void hist_kernel(const int* __restrict__ ei, unsigned* __restrict__ deg) {
    int e = blockIdx.x * blockDim.x + threadIdx.x;
    if (e >= E_TOT) return;
    int d = (e < N_EDGES) ? ei[N_EDGES + e] : (e - N_EDGES);
    atomicAdd(deg + d, 1u);
}

__global__ void scan_block_kernel(const unsigned* __restrict__ deg, unsigned* __restrict__ rs,
                                  unsigned* __restrict__ bsums, int n) {
    __shared__ unsigned buf[SCAN_BS];
    int i = blockIdx.x * SCAN_BS + threadIdx.x;
    unsigned v = (i < n) ? deg[i] : 0u;
    buf[threadIdx.x] = v;
    __syncthreads();
    for (int o = 1; o < SCAN_BS; o <<= 1) {
        unsigned t = (threadIdx.x >= (unsigned)o) ? buf[threadIdx.x - o] : 0u;
        __syncthreads();
        buf[threadIdx.x] += t;
        __syncthreads();
    }
    if (i < n) rs[i] = buf[threadIdx.x] - v;
    if (threadIdx.x == SCAN_BS - 1) bsums[blockIdx.x] = buf[SCAN_BS - 1];
}

__global__ void scan_fix_kernel(unsigned* __restrict__ rs, const unsigned* __restrict__ bsums,
                                unsigned* __restrict__ wptr, int n) {
    __shared__ unsigned s_off;
    int k = blockIdx.x >> 2;
    if (threadIdx.x < 64) {
        unsigned v = ((int)threadIdx.x < k) ? bsums[threadIdx.x] : 0u;
        #pragma unroll
        for (int o = 32; o; o >>= 1) v += __shfl_xor(v, o);
        if (threadIdx.x == 0) s_off = v;
    }
    __syncthreads();
    unsigned off = s_off;
    int i = blockIdx.x * 256 + threadIdx.x;
    if (i < n) {
        unsigned r = rs[i] + off;
        rs[i] = r;
        wptr[i] = r;
    }
    if (i == n) rs[n] = E_TOT;
}

__global__ void fill_win_kernel(const int* __restrict__ ei, unsigned* __restrict__ wptr,
                                int* __restrict__ srcs) {
    const int nb_e = (E_TOT + 255) / 256;
    int pass = blockIdx.x / nb_e;
    int eb   = blockIdx.x - pass * nb_e;
    int e = eb * 256 + threadIdx.x;
    if (e >= E_TOT) return;
    int lo = pass * FILL_WIN;
    int d = (e < N_EDGES) ? ei[N_EDGES + e] : (e - N_EDGES);
    if ((unsigned)(d - lo) >= (unsigned)FILL_WIN) return;
    int s = (e < N_EDGES) ? ei[e] : d;
    unsigned pos = atomicAdd(wptr + d, 1u);
    srcs[pos] = s;
}

// ---------------- layer-0 helpers (linearity: gather x, then GEMM) ----------------

// cast x (N*32 fp32) -> fp16
__global__ void xcast_kernel(const float* __restrict__ x, __half* __restrict__ xh) {
    int i = blockIdx.x * blockDim.x + threadIdx.x;   // uint2 index (4 halves)
    if (i >= N_NODES * 8) return;
    float4 f = ((const float4*)x)[i];
    __half2 a = __floats2half2_rn(f.x, f.y), b = __floats2half2_rn(f.z, f.w);
    uint2 st; st.x = *(unsigned*)&a; st.y = *(unsigned*)&b;
    ((uint2*)xh)[i] = st;
}

// u_s = W0 @ as0, u_d = W0 @ ad0  (32-vectors); one wave
__global__ void uproj_kernel(const float* __restrict__ W0, const float* __restrict__ as0,
                             const float* __restrict__ ad0, float* __restrict__ us,
                             float* __restrict__ ud) {
    int k = threadIdx.x & 31;
    int sel = threadIdx.x >> 5;
    const float* a = sel ? ad0 : as0;
    float acc = 0.f;
    for (int c = 0; c < HID; ++c) acc += W0[k * HID + c] * a[c];
    if (sel) ud[k] = acc; else us[k] = acc;
}

// es[i] = x[i,:]·u_s, ed[i] = x[i,:]·u_d   (2 nodes per wave, 32 lanes each)
__global__ void scores0_kernel(const float* __restrict__ x, const float* __restrict__ us,
                               const float* __restrict__ ud, float* __restrict__ es,
                               float* __restrict__ ed) {
    int idx = blockIdx.x * blockDim.x + threadIdx.x;
    int node = idx >> 5;                 // 2 nodes per wave
    int k = threadIdx.x & 31;
    float xv = x[(size_t)node * 32 + k];
    float ps = xv * us[k], pd = xv * ud[k];
    #pragma unroll
    for (int o = 16; o; o >>= 1) {
        ps += __shfl_xor(ps, o);
        pd += __shfl_xor(pd, o);
    }
    if (k == 0) { es[node] = ps; ed[node] = pd; }
}

// aggregate 32-dim fp16 x: agg[n,32] = sum alpha * x[src]. Wave per node,
// 8 lanes x uint2 (4ch) per row -> 8 rows per load instruction.
__global__ __launch_bounds__(256) void aggregate32_kernel(
    const unsigned* __restrict__ rs, const int* __restrict__ srcs,
    const float* __restrict__ es, const float* __restrict__ ed,
    const __half* __restrict__ xh, float* __restrict__ agg) {
    __shared__ uint2 sh[4][MAXD];
    int node = (int)((blockIdx.x * (long long)blockDim.x + threadIdx.x) >> 6);
    int lane = threadIdx.x & 63;
    int wv = threadIdx.x >> 6;
    int grp = lane >> 3, lin = lane & 7;
    unsigned row = rs[node];
    int deg = (int)(rs[node + 1] - row);
    float edv = ed[node];

    float lsum = 0.f;
    float4 acc = {0.f, 0.f, 0.f, 0.f};
    const uint2* x2 = (const uint2*)xh;   // row = 8 uint2

    for (int base = 0; base < deg; base += MAXD) {
        int cnt = min(MAXD, deg - base);
        for (int j = lane; j < cnt; j += 64) {
            int s = srcs[row + base + j];
            float v = es[s] + edv;
            v = v > 0.f ? v : NEG_SLOPE * v;
            float e = __expf(v);
            uint2 p; p.x = (unsigned)s; p.y = __float_as_uint(e);
            sh[wv][j] = p;
            lsum += e;
        }
        for (int jb = 0; jb < cnt; jb += 8) {
            int r = jb + grp;
            if (r < cnt) {
                uint2 p = sh[wv][r];
                float e = __uint_as_float(p.y);
                uint2 q = x2[(size_t)p.x * 8 + lin];
                float2 fa = __half22float2(*(__half2*)&q.x);
                float2 fb = __half22float2(*(__half2*)&q.y);
                acc.x += e * fa.x; acc.y += e * fa.y;
                acc.z += e * fb.x; acc.w += e * fb.y;
            }
        }
    }
    #pragma unroll
    for (int o = 32; o; o >>= 1) lsum += __shfl_xor(lsum, o);
    #pragma unroll
    for (int o = 8; o <= 32; o <<= 1) {
        acc.x += __shfl_xor(acc.x, o);
        acc.y += __shfl_xor(acc.y, o);
        acc.z += __shfl_xor(acc.z, o);
        acc.w += __shfl_xor(acc.w, o);
    }
    if (grp == 0) {
        float inv = 1.f / lsum;
        float4 o4; o4.x = acc.x * inv; o4.y = acc.y * inv; o4.z = acc.z * inv; o4.w = acc.w * inv;
        ((float4*)agg)[(size_t)node * 8 + lin] = o4;
    }
}

// out = relu(agg @ W0 + b0), fp32 output (layer-0 epilogue GEMM, din=32)
__global__ void gemm32_kernel(const float* __restrict__ agg, const float* __restrict__ W,
                              const float* __restrict__ b, float* __restrict__ out) {
    int idx = blockIdx.x * blockDim.x + threadIdx.x;   // (n/4)*24 threads
    if (idx >= (N_NODES / 4) * 24) return;
    int g   = idx / 24;
    int c4q = idx - g * 24;
    int n0 = g * 4;
    const float4* Xa = (const float4*)agg + (size_t)n0 * 8;
    const float4* Xb = Xa + 8;
    const float4* Xc = Xb + 8;
    const float4* Xd = Xc + 8;
    const float4* W4 = (const float4*)W;   // row stride 24 float4

    float4 accA = {0,0,0,0}, accB = {0,0,0,0}, accC = {0,0,0,0}, accD = {0,0,0,0};
    for (int k4 = 0; k4 < 8; ++k4) {
        float4 xa = Xa[k4], xb = Xb[k4], xc = Xc[k4], xd = Xd[k4];
        #pragma unroll
        for (int kk = 0; kk < 4; ++kk) {
            float4 w = W4[(size_t)(k4 * 4 + kk) * 24 + c4q];
            float sa = ((const float*)&xa)[kk], sb = ((const float*)&xb)[kk];
            float sc = ((const float*)&xc)[kk], sd = ((const float*)&xd)[kk];
            accA.x += sa * w.x; accA.y += sa * w.y; accA.z += sa * w.z; accA.w += sa * w.w;
            accB.x += sb * w.x; accB.y += sb * w.y; accB.z += sb * w.z; accB.w += sb * w.w;
            accC.x += sc * w.x; accC.y += sc * w.y; accC.z += sc * w.z; accC.w += sc * w.w;
            accD.x += sd * w.x; accD.y += sd * w.y; accD.z += sd * w.z; accD.w += sd * w.w;
        }
    }
    float4 bb = ((const float4*)b)[c4q];
    float4* O = (float4*)out;
    float4 r;
    r.x = fmaxf(accA.x + bb.x, 0.f); r.y = fmaxf(accA.y + bb.y, 0.f);
    r.z = fmaxf(accA.z + bb.z, 0.f); r.w = fmaxf(accA.w + bb.w, 0.f);
    O[(size_t)n0 * 24 + c4q] = r;
    r.x = fmaxf(accB.x + bb.x, 0.f); r.y = fmaxf(accB.y + bb.y, 0.f);
    r.z = fmaxf(accB.z + bb.z, 0.f); r.w = fmaxf(accB.w + bb.w, 0.f);
    O[(size_t)(n0 + 1) * 24 + c4q] = r;
    r.x = fmaxf(accC.x + bb.x, 0.f); r.y = fmaxf(accC.y + bb.y, 0.f);
    r.z = fmaxf(accC.z + bb.z, 0.f); r.w = fmaxf(accC.w + bb.w, 0.f);
    O[(size_t)(n0 + 2) * 24 + c4q] = r;
    r.x = fmaxf(accD.x + bb.x, 0.f); r.y = fmaxf(accD.y + bb.y, 0.f);
    r.z = fmaxf(accD.z + bb.z, 0.f); r.w = fmaxf(accD.w + bb.w, 0.f);
    O[(size_t)(n0 + 3) * 24 + c4q] = r;
}

// ---------------- layers 1,2: GEMM to contiguous fp16 h ----------------

__device__ __forceinline__ void fma4(float4& a, float s, const float4& w) {
    a.x += s * w.x; a.y += s * w.y; a.z += s * w.z; a.w += s * w.w;
}

__global__ void gemm_h16_kernel(const float* __restrict__ x, const float* __restrict__ W,
                                __half* __restrict__ h, int n, int din) {
    int idx = blockIdx.x * blockDim.x + threadIdx.x;   // (n/4)*24 threads
    int ngroups = n >> 2;
    if (idx >= ngroups * 24) return;
    int g   = idx / 24;
    int c4q = idx - g * 24;
    int n0 = g * 4;
    int k4n = din >> 2;
    const float4* X4 = (const float4*)x;
    const float4* W4 = (const float4*)W;
    const float4* Xa = X4 + (size_t)n0 * k4n;
    const float4* Xb = Xa + k4n;
    const float4* Xc = Xb + k4n;
    const float4* Xd = Xc + k4n;

    float4 accA = {0,0,0,0}, accB = {0,0,0,0}, accC = {0,0,0,0}, accD = {0,0,0,0};
    for (int k4 = 0; k4 < k4n; ++k4) {
        float4 xa = Xa[k4], xb = Xb[k4], xc = Xc[k4], xd = Xd[k4];
        #pragma unroll
        for (int kk = 0; kk < 4; ++kk) {
            float4 w = W4[(size_t)(k4 * 4 + kk) * 24 + c4q];
            fma4(accA, ((const float*)&xa)[kk], w);
            fma4(accB, ((const float*)&xb)[kk], w);
            fma4(accC, ((const float*)&xc)[kk], w);
            fma4(accD, ((const float*)&xd)[kk], w);
        }
    }
    __half2* H2 = (__half2*)h;
    size_t rb = (size_t)n0 * 48 + c4q * 2;
    {
        __half2 p0 = __floats2half2_rn(accA.x, accA.y), p1 = __floats2half2_rn(accA.z, accA.w);
        uint2 st; st.x = *(unsigned*)&p0; st.y = *(unsigned*)&p1;
        *(uint2*)(H2 + rb) = st;
    }
    {
        __half2 p0 = __floats2half2_rn(accB.x, accB.y), p1 = __floats2half2_rn(accB.z, accB.w);
        uint2 st; st.x = *(unsigned*)&p0; st.y = *(unsigned*)&p1;
        *(uint2*)(H2 + rb + 48) = st;
    }
    {
        __half2 p0 = __floats2half2_rn(accC.x, accC.y), p1 = __floats2half2_rn(accC.z, accC.w);
        uint2 st; st.x = *(unsigned*)&p0; st.y = *(unsigned*)&p1;
        *(uint2*)(H2 + rb + 96) = st;
    }
    {
        __half2 p0 = __floats2half2_rn(accD.x, accD.y), p1 = __floats2half2_rn(accD.z, accD.w);
        uint2 st; st.x = *(unsigned*)&p0; st.y = *(unsigned*)&p1;
        *(uint2*)(H2 + rb + 144) = st;
    }
}

// es/ed from contiguous fp16 h (wave per node, 48 lanes)
__global__ void scores_kernel(const __half* __restrict__ h, const float* __restrict__ a_s,
                              const float* __restrict__ a_d, float* __restrict__ es,
                              float* __restrict__ ed, int n) {
    int node = (int)((blockIdx.x * (long long)blockDim.x + threadIdx.x) >> 6);
    int lane = threadIdx.x & 63;
    if (node >= n) return;
    float ps = 0.f, pd = 0.f;
    if (lane < 48) {
        const __half2* h2 = (const __half2*)h + (size_t)node * 48;
        float2 hv = __half22float2(h2[lane]);
        float2 sv = ((const float2*)a_s)[lane];
        float2 dv = ((const float2*)a_d)[lane];
        ps = hv.x * sv.x + hv.y * sv.y;
        pd = hv.x * dv.x + hv.y * dv.y;
    }
    #pragma unroll
    for (int o = 32; o; o >>= 1) {
        ps += __shfl_xor(ps, o);
        pd += __shfl_xor(pd, o);
    }
    if (lane == 0) { es[node] = ps; ed[node] = pd; }
}

__global__ void final_proj_kernel(const float* __restrict__ x, const float* __restrict__ Wf,
                                  const float* __restrict__ asf, const float* __restrict__ adf,
                                  float* __restrict__ h, float* __restrict__ es,
                                  float* __restrict__ ed, int n) {
    int node = (int)((blockIdx.x * (long long)blockDim.x + threadIdx.x) >> 6);
    int lane = threadIdx.x & 63;
    if (node >= n) return;
    const float* xr = x + (long long)node * HID;
    float p = 0.f;
    for (int c = lane; c < HID; c += 64) p += xr[c] * Wf[c];
    #pragma unroll
    for (int o = 32; o; o >>= 1) p += __shfl_xor(p, o);
    if (lane == 0) {
        h[node] = p;
        es[node] = p * asf[0];
        ed[node] = p * adf[0];
    }
}

// ---------------- fused softmax + gather (96ch): 2 rows per load instruction --------------
// Wave per node. Pass A: strided stage (src, exp) into LDS + lsum. Pass C: lanes 0-23
// handle row j (uint2 = 4 fp16 ch each), lanes 32-55 row j+1; xor(32) combine.
__global__ __launch_bounds__(256) void aggregate96_kernel(
    const unsigned* __restrict__ rs, const int* __restrict__ srcs,
    const float* __restrict__ es, const float* __restrict__ ed,
    const __half* __restrict__ h, const float* __restrict__ b,
    const float* __restrict__ res, float* __restrict__ out, int do_relu) {
    __shared__ uint2 sh[4][MAXD];
    int node = (int)((blockIdx.x * (long long)blockDim.x + threadIdx.x) >> 6);
    int lane = threadIdx.x & 63;
    int wv = threadIdx.x >> 6;
    int half = lane >> 5, lin = lane & 31;
    unsigned row = rs[node];
    int deg = (int)(rs[node + 1] - row);
    float edv = ed[node];

    float lsum = 0.f;
    float4 acc = {0.f, 0.f, 0.f, 0.f};
    const uint2* h4 = (const uint2*)h;    // row = 24 uint2 (96 halves)

    for (int base = 0; base < deg; base += MAXD) {
        int cnt = min(MAXD, deg - base);
        for (int j = lane; j < cnt; j += 64) {
            int s = srcs[row + base + j];
            float v = es[s] + edv;
            v = v > 0.f ? v : NEG_SLOPE * v;
            float e = __expf(v);
            uint2 p; p.x = (unsigned)s; p.y = __float_as_uint(e);
            sh[wv][j] = p;   // same-wave RAW, ordered by lgkmcnt
            lsum += e;
        }
        for (int jb = 0; jb < cnt; jb += 2) {
            int r = jb + half;
            if (lin < 24 && r < cnt) {
                uint2 p = sh[wv][r];
                float e = __uint_as_float(p.y);
                uint2 q = h4[(size_t)p.x * 24 + lin];
                float2 fa = __half22float2(*(__half2*)&q.x);
                float2 fb = __half22float2(*(__half2*)&q.y);
                acc.x += e * fa.x; acc.y += e * fa.y;
                acc.z += e * fb.x; acc.w += e * fb.y;
            }
        }
    }
    #pragma unroll
    for (int o = 32; o; o >>= 1) lsum += __shfl_xor(lsum, o);
    acc.x += __shfl_xor(acc.x, 32);
    acc.y += __shfl_xor(acc.y, 32);
    acc.z += __shfl_xor(acc.z, 32);
    acc.w += __shfl_xor(acc.w, 32);

    if (half == 0 && lin < 24) {
        float inv = 1.f / lsum;
        float4 bb = ((const float4*)b)[lin];
        float4 v;
        v.x = acc.x * inv + bb.x; v.y = acc.y * inv + bb.y;
        v.z = acc.z * inv + bb.z; v.w = acc.w * inv + bb.w;
        if (res) {
            float4 rr = ((const float4*)res)[(size_t)node * 24 + lin];
            v.x += rr.x; v.y += rr.y; v.z += rr.z; v.w += rr.w;
        }
        if (do_relu) {
            v.x = fmaxf(v.x, 0.f); v.y = fmaxf(v.y, 0.f);
            v.z = fmaxf(v.z, 0.f); v.w = fmaxf(v.w, 0.f);
        }
        ((float4*)out)[(size_t)node * 24 + lin] = v;
    }
}

// ---------------- dout=1 aggregate (final layer): single pass, no max ----------------
__global__ __launch_bounds__(256) void aggregate1_kernel(
    const unsigned* __restrict__ rs, const int* __restrict__ srcs,
    const float* __restrict__ es, const float* __restrict__ ed,
    const float* __restrict__ h, const float* __restrict__ b,
    float* __restrict__ out) {
    int node = (int)((blockIdx.x * (long long)blockDim.x + threadIdx.x) >> 6);
    int lane = threadIdx.x & 63;
    unsigned row = rs[node];
    int deg = (int)(rs[node + 1] - row);
    float edv = ed[node];

    float lsum = 0.f, acc = 0.f;
    for (int j = lane; j < deg; j += 64) {
        int s = srcs[row + j];
        float v = es[s] + edv;
        v = v > 0.f ? v : NEG_SLOPE * v;
        float ex = __expf(v);
        lsum += ex;
        acc += ex * h[s];
    }
    #pragma unroll
    for (int o = 32; o; o >>= 1) {
        lsum += __shfl_xor(lsum, o);
        acc  += __shfl_xor(acc, o);
    }
    if (lane == 0) out[node] = acc / lsum + b[0];
}

// ---------------- host-side orchestration ----------------

extern "C" void kernel_launch(void* const* d_in, const int* in_sizes, int n_in,
                              void* d_out, int out_size, void* d_ws, size_t ws_size,
                              hipStream_t stream) {
    const float* x  = (const float*)d_in[0];
    const int*   ei = (const int*)d_in[1];
    const float* W0 = (const float*)d_in[3];
    const float* as0 = (const float*)d_in[4];
    const float* ad0 = (const float*)d_in[5];
    const float* b0 = (const float*)d_in[6];
    const float* W1 = (const float*)d_in[7];
    const float* as1 = (const float*)d_in[8];
    const float* ad1 = (const float*)d_in[9];
    const float* b1 = (const float*)d_in[10];
    const float* W2 = (const float*)d_in[11];
    const float* as2 = (const float*)d_in[12];
    const float* ad2 = (const float*)d_in[13];
    const float* b2 = (const float*)d_in[14];
    const float* Wf = (const float*)d_in[15];
    const float* asf = (const float*)d_in[16];
    const float* adf = (const float*)d_in[17];
    const float* bf = (const float*)d_in[18];

    float* out = (float*)d_out;  // 50000 floats

    // workspace carve-up
    float* Hf = (float*)d_ws;                    // N*96 float slot: fp16 h / XH / DEG / final fp32 h
    __half* H16 = (__half*)Hf;
    float* FA = Hf + (long long)N_NODES * HID;   // N*96
    float* FB = FA + (long long)N_NODES * HID;   // N*96 (also aliased as AGG during layer 0)
    float* ES = FB + (long long)N_NODES * HID;   // N
    float* ED = ES + N_NODES;                    // N
    unsigned* RS   = (unsigned*)(ED + N_NODES);  // N+1
    unsigned* WPTR = RS + (N_NODES + 1);         // N
    int* SRCS = (int*)(WPTR + N_NODES);          // E_TOT
    float* US = (float*)(SRCS + E_TOT);          // 32
    float* UD = US + 32;                         // 32
    unsigned* DEG = (unsigned*)Hf;               // CSR temps aliased onto Hf (used pre-xcast)
    unsigned* BS  = DEG + N_NODES;
    __half* XH = (__half*)Hf;                    // N*32 fp16 x, aliased onto Hf after CSR
    float* AGG = FB;                             // N*32 fp32, FB free during layer 0

    // ---- CSR build ----
    hipMemsetAsync(DEG, 0, (size_t)N_NODES * sizeof(unsigned), stream);
    hist_kernel<<<cdiv(E_TOT, 256), 256, 0, stream>>>(ei, DEG);
    scan_block_kernel<<<N_SCAN_BLOCKS, SCAN_BS, 0, stream>>>(DEG, RS, BS, N_NODES);
    scan_fix_kernel<<<cdiv(N_NODES + 1, 256), 256, 0, stream>>>(RS, BS, WPTR, N_NODES);
    {
        const int nb_e = cdiv(E_TOT, 256);
        fill_win_kernel<<<nb_e * FILL_PASSES, 256, 0, stream>>>(ei, WPTR, SRCS);
    }

    const int gemm_threads = (N_NODES / 4) * 24;   // 300000

    // ---- layer 0 (linearity): es/ed direct, gather fp16 x, then GEMM ----
    xcast_kernel<<<cdiv(N_NODES * 8, 256), 256, 0, stream>>>(x, XH);
    uproj_kernel<<<1, 64, 0, stream>>>(W0, as0, ad0, US, UD);
    scores0_kernel<<<cdiv(N_NODES * 32, 256), 256, 0, stream>>>(x, US, UD, ES, ED);
    aggregate32_kernel<<<NODE_BLOCKS, 256, 0, stream>>>(RS, SRCS, ES, ED, XH, AGG);
    gemm32_kernel<<<cdiv(gemm_threads, 256), 256, 0, stream>>>(AGG, W0, b0, FA);

    // ---- layer 1: FA -> FB, residual FA, relu ----
    gemm_h16_kernel<<<cdiv(gemm_threads, 256), 256, 0, stream>>>(FA, W1, H16, N_NODES, HID);
    scores_kernel<<<NODE_BLOCKS, 256, 0, stream>>>(H16, as1, ad1, ES, ED, N_NODES);
    aggregate96_kernel<<<NODE_BLOCKS, 256, 0, stream>>>(RS, SRCS, ES, ED, H16, b1, FA, FB, 1);

    // ---- layer 2: FB -> FA, residual FB, relu ----
    gemm_h16_kernel<<<cdiv(gemm_threads, 256), 256, 0, stream>>>(FB, W2, H16, N_NODES, HID);
    scores_kernel<<<NODE_BLOCKS, 256, 0, stream>>>(H16, as2, ad2, ES, ED, N_NODES);
    aggregate96_kernel<<<NODE_BLOCKS, 256, 0, stream>>>(RS, SRCS, ES, ED, H16, b2, FB, FA, 1);

    // ---- final: FA -> out (dout=1), fp32 path ----
    final_proj_kernel<<<NODE_BLOCKS, 256, 0, stream>>>(FA, Wf, asf, adf, Hf, ES, ED, N_NODES);
    aggregate1_kernel<<<NODE_BLOCKS, 256, 0, stream>>>(RS, SRCS, ES, ED, Hf, bf, out);
}

// Round 8
// 408.454 us; speedup vs baseline: 1.4911x; 1.0200x over previous
//
#include <hip/hip_runtime.h>
#include <hip/hip_fp16.h>
#include <math.h>

#define N_NODES 50000
#define N_EDGES 800000
#define E_TOT   (N_EDGES + N_NODES)   // 850000, self-loops appended
#define IN_DIM  32
#define HID     96
#define NEG_SLOPE 0.2f
#define MAXD    128                   // LDS chunk per wave (per-chunk staging)
#define SCAN_BS 1024
#define N_SCAN_BLOCKS ((N_NODES + SCAN_BS - 1) / SCAN_BS)   // 49
#define FILL_PASSES 8
#define FILL_WIN (N_NODES / FILL_PASSES)   // 6250
#define NODE_BLOCKS (N_NODES / 4)          // 12500 blocks of 4 waves/nodes

static inline int cdiv(long long a, int b) { return (int)((a + b - 1) / b); }

// ---------------- CSR build (counting sort by dst), once per launch ----------------

__global__ void hist_kernel(const int* __restrict__ ei, unsigned* __restrict__ deg) {
    int e = blockIdx.x * blockDim.x + threadIdx.x;
    if (e >= E_TOT) return;
    int d = (e < N_EDGES) ? ei[N_EDGES + e] : (e - N_EDGES);
    atomicAdd(deg + d, 1u);
}

__global__ void scan_block_kernel(const unsigned* __restrict__ deg, unsigned* __restrict__ rs,
                                  unsigned* __restrict__ bsums, int n) {
    __shared__ unsigned buf[SCAN_BS];
    int i = blockIdx.x * SCAN_BS + threadIdx.x;
    unsigned v = (i < n) ? deg[i] : 0u;
    buf[threadIdx.x] = v;
    __syncthreads();
    for (int o = 1; o < SCAN_BS; o <<= 1) {
        unsigned t = (threadIdx.x >= (unsigned)o) ? buf[threadIdx.x - o] : 0u;
        __syncthreads();
        buf[threadIdx.x] += t;
        __syncthreads();
    }
    if (i < n) rs[i] = buf[threadIdx.x] - v;
    if (threadIdx.x == SCAN_BS - 1) bsums[blockIdx.x] = buf[SCAN_BS - 1];
}

__global__ void scan_fix_kernel(unsigned* __restrict__ rs, const unsigned* __restrict__ bsums,
                                unsigned* __restrict__ wptr, int n) {
    __shared__ unsigned s_off;
    int k = blockIdx.x >> 2;
    if (threadIdx.x < 64) {
        unsigned v = ((int)threadIdx.x < k) ? bsums[threadIdx.x] : 0u;
        #pragma unroll
        for (int o = 32; o; o >>= 1) v += __shfl_xor(v, o);
        if (threadIdx.x == 0) s_off = v;
    }
    __syncthreads();
    unsigned off = s_off;
    int i = blockIdx.x * 256 + threadIdx.x;
    if (i < n) {
        unsigned r = rs[i] + off;
        rs[i] = r;
        wptr[i] = r;
    }
    if (i == n) rs[n] = E_TOT;
}

__global__ void fill_win_kernel(const int* __restrict__ ei, unsigned* __restrict__ wptr,
                                int* __restrict__ srcs) {
    const int nb_e = (E_TOT + 255) / 256;
    int pass = blockIdx.x / nb_e;
    int eb   = blockIdx.x - pass * nb_e;
    int e = eb * 256 + threadIdx.x;
    if (e >= E_TOT) return;
    int lo = pass * FILL_WIN;
    int d = (e < N_EDGES) ? ei[N_EDGES + e] : (e - N_EDGES);
    if ((unsigned)(d - lo) >= (unsigned)FILL_WIN) return;
    int s = (e < N_EDGES) ? ei[e] : d;
    unsigned pos = atomicAdd(wptr + d, 1u);
    srcs[pos] = s;
}

// ---------------- layer-0 fused prep: uproj + scores0 + xcast in one kernel -------------
// u_s = W0@as0, u_d = W0@ad0 computed per block (cheap); es/ed per node; x cast to fp16.
__global__ __launch_bounds__(256) void layer0_prep_kernel(
    const float* __restrict__ x, const float* __restrict__ W0,
    const float* __restrict__ as0, const float* __restrict__ ad0,
    __half* __restrict__ xh, float* __restrict__ es, float* __restrict__ ed) {
    __shared__ float s_us[32], s_ud[32];
    if (threadIdx.x < 64) {
        int k = threadIdx.x & 31;
        int sel = threadIdx.x >> 5;
        const float* a = sel ? ad0 : as0;
        float acc = 0.f;
        #pragma unroll 8
        for (int c = 0; c < HID; ++c) acc += W0[k * HID + c] * a[c];
        if (sel) s_ud[k] = acc; else s_us[k] = acc;
    }
    __syncthreads();
    int idx = blockIdx.x * 256 + threadIdx.x;   // grid = N*32 threads exactly
    int node = idx >> 5;
    int k = threadIdx.x & 31;
    float xv = x[(size_t)node * 32 + k];
    // fp16 cast, paired store (even lanes store half2)
    float xnb = __shfl_xor(xv, 1);
    if ((k & 1) == 0) {
        __half2 h2v = __floats2half2_rn(xv, xnb);
        ((__half2*)xh)[((size_t)node * 32 + k) >> 1] = h2v;
    }
    float ps = xv * s_us[k], pd = xv * s_ud[k];
    #pragma unroll
    for (int o = 16; o; o >>= 1) {
        ps += __shfl_xor(ps, o);
        pd += __shfl_xor(pd, o);
    }
    if (k == 0) { es[node] = ps; ed[node] = pd; }
}

// aggregate 32-dim fp16 x: agg[n,32] = softmax-weighted sum of x[src]. Wave per node,
// 8 lanes x uint2 (4ch) per row -> 8 rows per load instruction; x2 unrolled.
__global__ __launch_bounds__(256) void aggregate32_kernel(
    const unsigned* __restrict__ rs, const int* __restrict__ srcs,
    const float* __restrict__ es, const float* __restrict__ ed,
    const __half* __restrict__ xh, float* __restrict__ agg) {
    __shared__ uint2 sh[4][MAXD];
    int node = (int)((blockIdx.x * (long long)blockDim.x + threadIdx.x) >> 6);
    int lane = threadIdx.x & 63;
    int wv = threadIdx.x >> 6;
    int grp = lane >> 3, lin = lane & 7;
    unsigned row = rs[node];
    int deg = (int)(rs[node + 1] - row);
    float edv = ed[node];

    float lsum = 0.f;
    float4 acc = {0.f, 0.f, 0.f, 0.f};
    const uint2* x2 = (const uint2*)xh;   // row = 8 uint2

    for (int base = 0; base < deg; base += MAXD) {
        int cnt = min(MAXD, deg - base);
        for (int j = lane; j < cnt; j += 64) {
            int s = srcs[row + base + j];
            float v = es[s] + edv;
            v = v > 0.f ? v : NEG_SLOPE * v;
            float e = __expf(v);
            uint2 p; p.x = (unsigned)s; p.y = __float_as_uint(e);
            sh[wv][j] = p;
            lsum += e;
        }
        int jb = 0;
        for (; jb + 16 <= cnt; jb += 16) {
            uint2 pa = sh[wv][jb + grp];
            uint2 pb = sh[wv][jb + 8 + grp];
            uint2 qa = x2[(size_t)pa.x * 8 + lin];
            uint2 qb = x2[(size_t)pb.x * 8 + lin];
            float ea = __uint_as_float(pa.y), eb = __uint_as_float(pb.y);
            float2 fa0 = __half22float2(*(__half2*)&qa.x);
            float2 fa1 = __half22float2(*(__half2*)&qa.y);
            float2 fb0 = __half22float2(*(__half2*)&qb.x);
            float2 fb1 = __half22float2(*(__half2*)&qb.y);
            acc.x += ea * fa0.x + eb * fb0.x; acc.y += ea * fa0.y + eb * fb0.y;
            acc.z += ea * fa1.x + eb * fb1.x; acc.w += ea * fa1.y + eb * fb1.y;
        }
        for (; jb < cnt; jb += 8) {
            int r = jb + grp;
            if (r < cnt) {
                uint2 p = sh[wv][r];
                float e = __uint_as_float(p.y);
                uint2 q = x2[(size_t)p.x * 8 + lin];
                float2 fa = __half22float2(*(__half2*)&q.x);
                float2 fb = __half22float2(*(__half2*)&q.y);
                acc.x += e * fa.x; acc.y += e * fa.y;
                acc.z += e * fb.x; acc.w += e * fb.y;
            }
        }
    }
    #pragma unroll
    for (int o = 32; o; o >>= 1) lsum += __shfl_xor(lsum, o);
    #pragma unroll
    for (int o = 8; o <= 32; o <<= 1) {
        acc.x += __shfl_xor(acc.x, o);
        acc.y += __shfl_xor(acc.y, o);
        acc.z += __shfl_xor(acc.z, o);
        acc.w += __shfl_xor(acc.w, o);
    }
    if (grp == 0) {
        float inv = 1.f / lsum;
        float4 o4; o4.x = acc.x * inv; o4.y = acc.y * inv; o4.z = acc.z * inv; o4.w = acc.w * inv;
        ((float4*)agg)[(size_t)node * 8 + lin] = o4;
    }
}

// out = relu(agg @ W0 + b0), fp32 output (layer-0 epilogue GEMM, din=32)
__global__ void gemm32_kernel(const float* __restrict__ agg, const float* __restrict__ W,
                              const float* __restrict__ b, float* __restrict__ out) {
    int idx = blockIdx.x * blockDim.x + threadIdx.x;   // (n/4)*24 threads
    if (idx >= (N_NODES / 4) * 24) return;
    int g   = idx / 24;
    int c4q = idx - g * 24;
    int n0 = g * 4;
    const float4* Xa = (const float4*)agg + (size_t)n0 * 8;
    const float4* Xb = Xa + 8;
    const float4* Xc = Xb + 8;
    const float4* Xd = Xc + 8;
    const float4* W4 = (const float4*)W;   // row stride 24 float4

    float4 accA = {0,0,0,0}, accB = {0,0,0,0}, accC = {0,0,0,0}, accD = {0,0,0,0};
    for (int k4 = 0; k4 < 8; ++k4) {
        float4 xa = Xa[k4], xb = Xb[k4], xc = Xc[k4], xd = Xd[k4];
        #pragma unroll
        for (int kk = 0; kk < 4; ++kk) {
            float4 w = W4[(size_t)(k4 * 4 + kk) * 24 + c4q];
            float sa = ((const float*)&xa)[kk], sb = ((const float*)&xb)[kk];
            float sc = ((const float*)&xc)[kk], sd = ((const float*)&xd)[kk];
            accA.x += sa * w.x; accA.y += sa * w.y; accA.z += sa * w.z; accA.w += sa * w.w;
            accB.x += sb * w.x; accB.y += sb * w.y; accB.z += sb * w.z; accB.w += sb * w.w;
            accC.x += sc * w.x; accC.y += sc * w.y; accC.z += sc * w.z; accC.w += sc * w.w;
            accD.x += sd * w.x; accD.y += sd * w.y; accD.z += sd * w.z; accD.w += sd * w.w;
        }
    }
    float4 bb = ((const float4*)b)[c4q];
    float4* O = (float4*)out;
    float4 r;
    r.x = fmaxf(accA.x + bb.x, 0.f); r.y = fmaxf(accA.y + bb.y, 0.f);
    r.z = fmaxf(accA.z + bb.z, 0.f); r.w = fmaxf(accA.w + bb.w, 0.f);
    O[(size_t)n0 * 24 + c4q] = r;
    r.x = fmaxf(accB.x + bb.x, 0.f); r.y = fmaxf(accB.y + bb.y, 0.f);
    r.z = fmaxf(accB.z + bb.z, 0.f); r.w = fmaxf(accB.w + bb.w, 0.f);
    O[(size_t)(n0 + 1) * 24 + c4q] = r;
    r.x = fmaxf(accC.x + bb.x, 0.f); r.y = fmaxf(accC.y + bb.y, 0.f);
    r.z = fmaxf(accC.z + bb.z, 0.f); r.w = fmaxf(accC.w + bb.w, 0.f);
    O[(size_t)(n0 + 2) * 24 + c4q] = r;
    r.x = fmaxf(accD.x + bb.x, 0.f); r.y = fmaxf(accD.y + bb.y, 0.f);
    r.z = fmaxf(accD.z + bb.z, 0.f); r.w = fmaxf(accD.w + bb.w, 0.f);
    O[(size_t)(n0 + 3) * 24 + c4q] = r;
}

// ---------------- layers 1,2: GEMM to contiguous fp16 h ----------------

__device__ __forceinline__ void fma4(float4& a, float s, const float4& w) {
    a.x += s * w.x; a.y += s * w.y; a.z += s * w.z; a.w += s * w.w;
}

__global__ void gemm_h16_kernel(const float* __restrict__ x, const float* __restrict__ W,
                                __half* __restrict__ h, int n, int din) {
    int idx = blockIdx.x * blockDim.x + threadIdx.x;   // (n/4)*24 threads
    int ngroups = n >> 2;
    if (idx >= ngroups * 24) return;
    int g   = idx / 24;
    int c4q = idx - g * 24;
    int n0 = g * 4;
    int k4n = din >> 2;
    const float4* X4 = (const float4*)x;
    const float4* W4 = (const float4*)W;
    const float4* Xa = X4 + (size_t)n0 * k4n;
    const float4* Xb = Xa + k4n;
    const float4* Xc = Xb + k4n;
    const float4* Xd = Xc + k4n;

    float4 accA = {0,0,0,0}, accB = {0,0,0,0}, accC = {0,0,0,0}, accD = {0,0,0,0};
    for (int k4 = 0; k4 < k4n; ++k4) {
        float4 xa = Xa[k4], xb = Xb[k4], xc = Xc[k4], xd = Xd[k4];
        #pragma unroll
        for (int kk = 0; kk < 4; ++kk) {
            float4 w = W4[(size_t)(k4 * 4 + kk) * 24 + c4q];
            fma4(accA, ((const float*)&xa)[kk], w);
            fma4(accB, ((const float*)&xb)[kk], w);
            fma4(accC, ((const float*)&xc)[kk], w);
            fma4(accD, ((const float*)&xd)[kk], w);
        }
    }
    __half2* H2 = (__half2*)h;
    size_t rb = (size_t)n0 * 48 + c4q * 2;
    {
        __half2 p0 = __floats2half2_rn(accA.x, accA.y), p1 = __floats2half2_rn(accA.z, accA.w);
        uint2 st; st.x = *(unsigned*)&p0; st.y = *(unsigned*)&p1;
        *(uint2*)(H2 + rb) = st;
    }
    {
        __half2 p0 = __floats2half2_rn(accB.x, accB.y), p1 = __floats2half2_rn(accB.z, accB.w);
        uint2 st; st.x = *(unsigned*)&p0; st.y = *(unsigned*)&p1;
        *(uint2*)(H2 + rb + 48) = st;
    }
    {
        __half2 p0 = __floats2half2_rn(accC.x, accC.y), p1 = __floats2half2_rn(accC.z, accC.w);
        uint2 st; st.x = *(unsigned*)&p0; st.y = *(unsigned*)&p1;
        *(uint2*)(H2 + rb + 96) = st;
    }
    {
        __half2 p0 = __floats2half2_rn(accD.x, accD.y), p1 = __floats2half2_rn(accD.z, accD.w);
        uint2 st; st.x = *(unsigned*)&p0; st.y = *(unsigned*)&p1;
        *(uint2*)(H2 + rb + 144) = st;
    }
}

// es/ed from contiguous fp16 h (wave per node, 48 lanes)
__global__ void scores_kernel(const __half* __restrict__ h, const float* __restrict__ a_s,
                              const float* __restrict__ a_d, float* __restrict__ es,
                              float* __restrict__ ed, int n) {
    int node = (int)((blockIdx.x * (long long)blockDim.x + threadIdx.x) >> 6);
    int lane = threadIdx.x & 63;
    if (node >= n) return;
    float ps = 0.f, pd = 0.f;
    if (lane < 48) {
        const __half2* h2 = (const __half2*)h + (size_t)node * 48;
        float2 hv = __half22float2(h2[lane]);
        float2 sv = ((const float2*)a_s)[lane];
        float2 dv = ((const float2*)a_d)[lane];
        ps = hv.x * sv.x + hv.y * sv.y;
        pd = hv.x * dv.x + hv.y * dv.y;
    }
    #pragma unroll
    for (int o = 32; o; o >>= 1) {
        ps += __shfl_xor(ps, o);
        pd += __shfl_xor(pd, o);
    }
    if (lane == 0) { es[node] = ps; ed[node] = pd; }
}

__global__ void final_proj_kernel(const float* __restrict__ x, const float* __restrict__ Wf,
                                  const float* __restrict__ asf, const float* __restrict__ adf,
                                  float* __restrict__ h, float* __restrict__ es,
                                  float* __restrict__ ed, int n) {
    int node = (int)((blockIdx.x * (long long)blockDim.x + threadIdx.x) >> 6);
    int lane = threadIdx.x & 63;
    if (node >= n) return;
    const float* xr = x + (long long)node * HID;
    float p = 0.f;
    for (int c = lane; c < HID; c += 64) p += xr[c] * Wf[c];
    #pragma unroll
    for (int o = 32; o; o >>= 1) p += __shfl_xor(p, o);
    if (lane == 0) {
        h[node] = p;
        es[node] = p * asf[0];
        ed[node] = p * adf[0];
    }
}

// ---------------- fused softmax + gather (96ch): 8 rows per unrolled iteration ----------
// Wave per node. Pass A: strided stage (src, exp) into LDS + lsum. Pass B: lanes 0-23
// row j, lanes 32-55 row j+1; x4 unroll -> 4 independent global loads in flight.
__global__ __launch_bounds__(256) void aggregate96_kernel(
    const unsigned* __restrict__ rs, const int* __restrict__ srcs,
    const float* __restrict__ es, const float* __restrict__ ed,
    const __half* __restrict__ h, const float* __restrict__ b,
    const float* __restrict__ res, float* __restrict__ out, int do_relu) {
    __shared__ uint2 sh[4][MAXD];
    int node = (int)((blockIdx.x * (long long)blockDim.x + threadIdx.x) >> 6);
    int lane = threadIdx.x & 63;
    int wv = threadIdx.x >> 6;
    int half = lane >> 5, lin = lane & 31;
    unsigned row = rs[node];
    int deg = (int)(rs[node + 1] - row);
    float edv = ed[node];

    float lsum = 0.f;
    float4 acc = {0.f, 0.f, 0.f, 0.f};
    const uint2* h4 = (const uint2*)h;    // row = 24 uint2 (96 halves)
    bool act = (lin < 24);

    for (int base = 0; base < deg; base += MAXD) {
        int cnt = min(MAXD, deg - base);
        for (int j = lane; j < cnt; j += 64) {
            int s = srcs[row + base + j];
            float v = es[s] + edv;
            v = v > 0.f ? v : NEG_SLOPE * v;
            float e = __expf(v);
            uint2 p; p.x = (unsigned)s; p.y = __float_as_uint(e);
            sh[wv][j] = p;   // same-wave RAW, ordered by lgkmcnt
            lsum += e;
        }
        int jb = 0;
        for (; jb + 8 <= cnt; jb += 8) {
            uint2 pa = sh[wv][jb + half];
            uint2 pb = sh[wv][jb + 2 + half];
            uint2 pc = sh[wv][jb + 4 + half];
            uint2 pd = sh[wv][jb + 6 + half];
            if (act) {
                uint2 qa = h4[(size_t)pa.x * 24 + lin];
                uint2 qb = h4[(size_t)pb.x * 24 + lin];
                uint2 qc = h4[(size_t)pc.x * 24 + lin];
                uint2 qd = h4[(size_t)pd.x * 24 + lin];
                float ea = __uint_as_float(pa.y), eb = __uint_as_float(pb.y);
                float ec = __uint_as_float(pc.y), ef = __uint_as_float(pd.y);
                float2 a0 = __half22float2(*(__half2*)&qa.x), a1 = __half22float2(*(__half2*)&qa.y);
                float2 b0 = __half22float2(*(__half2*)&qb.x), b1 = __half22float2(*(__half2*)&qb.y);
                float2 c0 = __half22float2(*(__half2*)&qc.x), c1 = __half22float2(*(__half2*)&qc.y);
                float2 d0 = __half22float2(*(__half2*)&qd.x), d1 = __half22float2(*(__half2*)&qd.y);
                acc.x += ea * a0.x + eb * b0.x + ec * c0.x + ef * d0.x;
                acc.y += ea * a0.y + eb * b0.y + ec * c0.y + ef * d0.y;
                acc.z += ea * a1.x + eb * b1.x + ec * c1.x + ef * d1.x;
                acc.w += ea * a1.y + eb * b1.y + ec * c1.y + ef * d1.y;
            }
        }
        for (; jb < cnt; jb += 2) {
            int r = jb + half;
            if (act && r < cnt) {
                uint2 p = sh[wv][r];
                float e = __uint_as_float(p.y);
                uint2 q = h4[(size_t)p.x * 24 + lin];
                float2 fa = __half22float2(*(__half2*)&q.x);
                float2 fb = __half22float2(*(__half2*)&q.y);
                acc.x += e * fa.x; acc.y += e * fa.y;
                acc.z += e * fb.x; acc.w += e * fb.y;
            }
        }
    }
    #pragma unroll
    for (int o = 32; o; o >>= 1) lsum += __shfl_xor(lsum, o);
    acc.x += __shfl_xor(acc.x, 32);
    acc.y += __shfl_xor(acc.y, 32);
    acc.z += __shfl_xor(acc.z, 32);
    acc.w += __shfl_xor(acc.w, 32);

    if (half == 0 && lin < 24) {
        float inv = 1.f / lsum;
        float4 bb = ((const float4*)b)[lin];
        float4 v;
        v.x = acc.x * inv + bb.x; v.y = acc.y * inv + bb.y;
        v.z = acc.z * inv + bb.z; v.w = acc.w * inv + bb.w;
        if (res) {
            float4 rr = ((const float4*)res)[(size_t)node * 24 + lin];
            v.x += rr.x; v.y += rr.y; v.z += rr.z; v.w += rr.w;
        }
        if (do_relu) {
            v.x = fmaxf(v.x, 0.f); v.y = fmaxf(v.y, 0.f);
            v.z = fmaxf(v.z, 0.f); v.w = fmaxf(v.w, 0.f);
        }
        ((float4*)out)[(size_t)node * 24 + lin] = v;
    }
}

// ---------------- dout=1 aggregate (final layer): single pass, no max ----------------
__global__ __launch_bounds__(256) void aggregate1_kernel(
    const unsigned* __restrict__ rs, const int* __restrict__ srcs,
    const float* __restrict__ es, const float* __restrict__ ed,
    const float* __restrict__ h, const float* __restrict__ b,
    float* __restrict__ out) {
    int node = (int)((blockIdx.x * (long long)blockDim.x + threadIdx.x) >> 6);
    int lane = threadIdx.x & 63;
    unsigned row = rs[node];
    int deg = (int)(rs[node + 1] - row);
    float edv = ed[node];

    float lsum = 0.f, acc = 0.f;
    for (int j = lane; j < deg; j += 64) {
        int s = srcs[row + j];
        float v = es[s] + edv;
        v = v > 0.f ? v : NEG_SLOPE * v;
        float ex = __expf(v);
        lsum += ex;
        acc += ex * h[s];
    }
    #pragma unroll
    for (int o = 32; o; o >>= 1) {
        lsum += __shfl_xor(lsum, o);
        acc  += __shfl_xor(acc, o);
    }
    if (lane == 0) out[node] = acc / lsum + b[0];
}

// ---------------- host-side orchestration ----------------

extern "C" void kernel_launch(void* const* d_in, const int* in_sizes, int n_in,
                              void* d_out, int out_size, void* d_ws, size_t ws_size,
                              hipStream_t stream) {
    const float* x  = (const float*)d_in[0];
    const int*   ei = (const int*)d_in[1];
    const float* W0 = (const float*)d_in[3];
    const float* as0 = (const float*)d_in[4];
    const float* ad0 = (const float*)d_in[5];
    const float* b0 = (const float*)d_in[6];
    const float* W1 = (const float*)d_in[7];
    const float* as1 = (const float*)d_in[8];
    const float* ad1 = (const float*)d_in[9];
    const float* b1 = (const float*)d_in[10];
    const float* W2 = (const float*)d_in[11];
    const float* as2 = (const float*)d_in[12];
    const float* ad2 = (const float*)d_in[13];
    const float* b2 = (const float*)d_in[14];
    const float* Wf = (const float*)d_in[15];
    const float* asf = (const float*)d_in[16];
    const float* adf = (const float*)d_in[17];
    const float* bf = (const float*)d_in[18];

    float* out = (float*)d_out;  // 50000 floats

    // workspace carve-up
    float* Hf = (float*)d_ws;                    // N*96 float slot: fp16 h / XH / DEG / final fp32 h
    __half* H16 = (__half*)Hf;
    float* FA = Hf + (long long)N_NODES * HID;   // N*96
    float* FB = FA + (long long)N_NODES * HID;   // N*96 (aliased as AGG during layer 0)
    float* ES = FB + (long long)N_NODES * HID;   // N
    float* ED = ES + N_NODES;                    // N
    unsigned* RS   = (unsigned*)(ED + N_NODES);  // N+1
    unsigned* WPTR = RS + (N_NODES + 1);         // N
    int* SRCS = (int*)(WPTR + N_NODES);          // E_TOT
    unsigned* DEG = (unsigned*)Hf;               // CSR temps aliased onto Hf (pre-prep)
    unsigned* BS  = DEG + N_NODES;
    __half* XH = (__half*)Hf;                    // N*32 fp16 x, aliased onto Hf after CSR
    float* AGG = FB;                             // N*32 fp32, FB free during layer 0

    // ---- CSR build ----
    hipMemsetAsync(DEG, 0, (size_t)N_NODES * sizeof(unsigned), stream);
    hist_kernel<<<cdiv(E_TOT, 256), 256, 0, stream>>>(ei, DEG);
    scan_block_kernel<<<N_SCAN_BLOCKS, SCAN_BS, 0, stream>>>(DEG, RS, BS, N_NODES);
    scan_fix_kernel<<<cdiv(N_NODES + 1, 256), 256, 0, stream>>>(RS, BS, WPTR, N_NODES);
    {
        const int nb_e = cdiv(E_TOT, 256);
        fill_win_kernel<<<nb_e * FILL_PASSES, 256, 0, stream>>>(ei, WPTR, SRCS);
    }

    const int gemm_threads = (N_NODES / 4) * 24;   // 300000

    // ---- layer 0 (linearity): fused prep, gather fp16 x, then GEMM ----
    layer0_prep_kernel<<<(N_NODES * 32) / 256, 256, 0, stream>>>(x, W0, as0, ad0, XH, ES, ED);
    aggregate32_kernel<<<NODE_BLOCKS, 256, 0, stream>>>(RS, SRCS, ES, ED, XH, AGG);
    gemm32_kernel<<<cdiv(gemm_threads, 256), 256, 0, stream>>>(AGG, W0, b0, FA);

    // ---- layer 1: FA -> FB, residual FA, relu ----
    gemm_h16_kernel<<<cdiv(gemm_threads, 256), 256, 0, stream>>>(FA, W1, H16, N_NODES, HID);
    scores_kernel<<<NODE_BLOCKS, 256, 0, stream>>>(H16, as1, ad1, ES, ED, N_NODES);
    aggregate96_kernel<<<NODE_BLOCKS, 256, 0, stream>>>(RS, SRCS, ES, ED, H16, b1, FA, FB, 1);

    // ---- layer 2: FB -> FA, residual FB, relu ----
    gemm_h16_kernel<<<cdiv(gemm_threads, 256), 256, 0, stream>>>(FB, W2, H16, N_NODES, HID);
    scores_kernel<<<NODE_BLOCKS, 256, 0, stream>>>(H16, as2, ad2, ES, ED, N_NODES);
    aggregate96_kernel<<<NODE_BLOCKS, 256, 0, stream>>>(RS, SRCS, ES, ED, H16, b2, FB, FA, 1);

    // ---- final: FA -> out (dout=1), fp32 path ----
    final_proj_kernel<<<NODE_BLOCKS, 256, 0, stream>>>(FA, Wf, asf, adf, Hf, ES, ED, N_NODES);
    aggregate1_kernel<<<NODE_BLOCKS, 256, 0, stream>>>(RS, SRCS, ES, ED, Hf, bf, out);
}

// Round 9
// 403.224 us; speedup vs baseline: 1.5105x; 1.0130x over previous
//
#include <hip/hip_runtime.h>
#include <hip/hip_fp16.h>
#include <math.h>

#define N_NODES 50000
#define N_EDGES 800000
#define E_TOT   (N_EDGES + N_NODES)   // 850000, self-loops appended
#define IN_DIM  32
#define HID     96
#define NEG_SLOPE 0.2f
#define MAXD    128                   // LDS chunk per wave (per-chunk staging)
#define SCAN_BS 1024
#define N_SCAN_BLOCKS ((N_NODES + SCAN_BS - 1) / SCAN_BS)   // 49
#define FILL_PASSES 8
#define FILL_WIN (N_NODES / FILL_PASSES)   // 6250
#define NODE_BLOCKS (N_NODES / 4)          // 12500 blocks of 4 waves/nodes

static inline int cdiv(long long a, int b) { return (int)((a + b - 1) / b); }

// ---------------- CSR build (counting sort by dst), once per launch ----------------
// Both hist and fill are windowed with pass = blockIdx & 7: with round-robin
// blockIdx->XCD mapping, all writes for a dst-window come from ONE XCD's L2,
// so srcs/deg lines fill completely before eviction (kills write amplification).

__global__ void hist_win_kernel(const int* __restrict__ ei, unsigned* __restrict__ deg) {
    int pass = blockIdx.x & 7;
    int eb   = blockIdx.x >> 3;
    int e = eb * 256 + threadIdx.x;
    if (e >= E_TOT) return;
    int d = (e < N_EDGES) ? ei[N_EDGES + e] : (e - N_EDGES);
    if ((unsigned)(d - pass * FILL_WIN) >= (unsigned)FILL_WIN) return;
    atomicAdd(deg + d, 1u);
}

__global__ void scan_block_kernel(const unsigned* __restrict__ deg, unsigned* __restrict__ rs,
                                  unsigned* __restrict__ bsums, int n) {
    __shared__ unsigned buf[SCAN_BS];
    int i = blockIdx.x * SCAN_BS + threadIdx.x;
    unsigned v = (i < n) ? deg[i] : 0u;
    buf[threadIdx.x] = v;
    __syncthreads();
    for (int o = 1; o < SCAN_BS; o <<= 1) {
        unsigned t = (threadIdx.x >= (unsigned)o) ? buf[threadIdx.x - o] : 0u;
        __syncthreads();
        buf[threadIdx.x] += t;
        __syncthreads();
    }
    if (i < n) rs[i] = buf[threadIdx.x] - v;
    if (threadIdx.x == SCAN_BS - 1) bsums[blockIdx.x] = buf[SCAN_BS - 1];
}

__global__ void scan_fix_kernel(unsigned* __restrict__ rs, const unsigned* __restrict__ bsums,
                                unsigned* __restrict__ wptr, int n) {
    __shared__ unsigned s_off;
    int k = blockIdx.x >> 2;
    if (threadIdx.x < 64) {
        unsigned v = ((int)threadIdx.x < k) ? bsums[threadIdx.x] : 0u;
        #pragma unroll
        for (int o = 32; o; o >>= 1) v += __shfl_xor(v, o);
        if (threadIdx.x == 0) s_off = v;
    }
    __syncthreads();
    unsigned off = s_off;
    int i = blockIdx.x * 256 + threadIdx.x;
    if (i < n) {
        unsigned r = rs[i] + off;
        rs[i] = r;
        wptr[i] = r;
    }
    if (i == n) rs[n] = E_TOT;
}

__global__ void fill_win_kernel(const int* __restrict__ ei, unsigned* __restrict__ wptr,
                                int* __restrict__ srcs) {
    int pass = blockIdx.x & 7;          // XCD-pinned pass (round-robin block->XCD)
    int eb   = blockIdx.x >> 3;
    int e = eb * 256 + threadIdx.x;
    if (e >= E_TOT) return;
    int lo = pass * FILL_WIN;
    int d = (e < N_EDGES) ? ei[N_EDGES + e] : (e - N_EDGES);
    if ((unsigned)(d - lo) >= (unsigned)FILL_WIN) return;
    int s = (e < N_EDGES) ? ei[e] : d;
    unsigned pos = atomicAdd(wptr + d, 1u);
    srcs[pos] = s;
}

// ---------------- layer-0 fused prep: uproj + scores0 + xcast in one kernel -------------
__global__ __launch_bounds__(256) void layer0_prep_kernel(
    const float* __restrict__ x, const float* __restrict__ W0,
    const float* __restrict__ as0, const float* __restrict__ ad0,
    __half* __restrict__ xh, float* __restrict__ es, float* __restrict__ ed) {
    __shared__ float s_us[32], s_ud[32];
    if (threadIdx.x < 64) {
        int k = threadIdx.x & 31;
        int sel = threadIdx.x >> 5;
        const float* a = sel ? ad0 : as0;
        float acc = 0.f;
        #pragma unroll 8
        for (int c = 0; c < HID; ++c) acc += W0[k * HID + c] * a[c];
        if (sel) s_ud[k] = acc; else s_us[k] = acc;
    }
    __syncthreads();
    int idx = blockIdx.x * 256 + threadIdx.x;   // grid = N*32 threads exactly
    int node = idx >> 5;
    int k = threadIdx.x & 31;
    float xv = x[(size_t)node * 32 + k];
    float xnb = __shfl_xor(xv, 1);
    if ((k & 1) == 0) {
        __half2 h2v = __floats2half2_rn(xv, xnb);
        ((__half2*)xh)[((size_t)node * 32 + k) >> 1] = h2v;
    }
    float ps = xv * s_us[k], pd = xv * s_ud[k];
    #pragma unroll
    for (int o = 16; o; o >>= 1) {
        ps += __shfl_xor(ps, o);
        pd += __shfl_xor(pd, o);
    }
    if (k == 0) { es[node] = ps; ed[node] = pd; }
}

// aggregate 32-dim fp16 x: agg[n,32] = softmax-weighted sum of x[src].
__global__ __launch_bounds__(256) void aggregate32_kernel(
    const unsigned* __restrict__ rs, const int* __restrict__ srcs,
    const float* __restrict__ es, const float* __restrict__ ed,
    const __half* __restrict__ xh, float* __restrict__ agg) {
    __shared__ uint2 sh[4][MAXD];
    int node = (int)((blockIdx.x * (long long)blockDim.x + threadIdx.x) >> 6);
    int lane = threadIdx.x & 63;
    int wv = threadIdx.x >> 6;
    int grp = lane >> 3, lin = lane & 7;
    unsigned row = rs[node];
    int deg = (int)(rs[node + 1] - row);
    float edv = ed[node];

    float lsum = 0.f;
    float4 acc = {0.f, 0.f, 0.f, 0.f};
    const uint2* x2 = (const uint2*)xh;   // row = 8 uint2

    for (int base = 0; base < deg; base += MAXD) {
        int cnt = min(MAXD, deg - base);
        for (int j = lane; j < cnt; j += 64) {
            int s = srcs[row + base + j];
            float v = es[s] + edv;
            v = v > 0.f ? v : NEG_SLOPE * v;
            float e = __expf(v);
            uint2 p; p.x = (unsigned)s; p.y = __float_as_uint(e);
            sh[wv][j] = p;
            lsum += e;
        }
        int jb = 0;
        for (; jb + 16 <= cnt; jb += 16) {
            uint2 pa = sh[wv][jb + grp];
            uint2 pb = sh[wv][jb + 8 + grp];
            uint2 qa = x2[(size_t)pa.x * 8 + lin];
            uint2 qb = x2[(size_t)pb.x * 8 + lin];
            float ea = __uint_as_float(pa.y), eb = __uint_as_float(pb.y);
            float2 fa0 = __half22float2(*(__half2*)&qa.x);
            float2 fa1 = __half22float2(*(__half2*)&qa.y);
            float2 fb0 = __half22float2(*(__half2*)&qb.x);
            float2 fb1 = __half22float2(*(__half2*)&qb.y);
            acc.x += ea * fa0.x + eb * fb0.x; acc.y += ea * fa0.y + eb * fb0.y;
            acc.z += ea * fa1.x + eb * fb1.x; acc.w += ea * fa1.y + eb * fb1.y;
        }
        for (; jb < cnt; jb += 8) {
            int r = jb + grp;
            if (r < cnt) {
                uint2 p = sh[wv][r];
                float e = __uint_as_float(p.y);
                uint2 q = x2[(size_t)p.x * 8 + lin];
                float2 fa = __half22float2(*(__half2*)&q.x);
                float2 fb = __half22float2(*(__half2*)&q.y);
                acc.x += e * fa.x; acc.y += e * fa.y;
                acc.z += e * fb.x; acc.w += e * fb.y;
            }
        }
    }
    #pragma unroll
    for (int o = 32; o; o >>= 1) lsum += __shfl_xor(lsum, o);
    #pragma unroll
    for (int o = 8; o <= 32; o <<= 1) {
        acc.x += __shfl_xor(acc.x, o);
        acc.y += __shfl_xor(acc.y, o);
        acc.z += __shfl_xor(acc.z, o);
        acc.w += __shfl_xor(acc.w, o);
    }
    if (grp == 0) {
        float inv = 1.f / lsum;
        float4 o4; o4.x = acc.x * inv; o4.y = acc.y * inv; o4.z = acc.z * inv; o4.w = acc.w * inv;
        ((float4*)agg)[(size_t)node * 8 + lin] = o4;
    }
}

// out = relu(agg @ W0 + b0), fp32 output (layer-0 epilogue GEMM, din=32)
__global__ void gemm32_kernel(const float* __restrict__ agg, const float* __restrict__ W,
                              const float* __restrict__ b, float* __restrict__ out) {
    int idx = blockIdx.x * blockDim.x + threadIdx.x;   // (n/4)*24 threads
    if (idx >= (N_NODES / 4) * 24) return;
    int g   = idx / 24;
    int c4q = idx - g * 24;
    int n0 = g * 4;
    const float4* Xa = (const float4*)agg + (size_t)n0 * 8;
    const float4* Xb = Xa + 8;
    const float4* Xc = Xb + 8;
    const float4* Xd = Xc + 8;
    const float4* W4 = (const float4*)W;   // row stride 24 float4

    float4 accA = {0,0,0,0}, accB = {0,0,0,0}, accC = {0,0,0,0}, accD = {0,0,0,0};
    for (int k4 = 0; k4 < 8; ++k4) {
        float4 xa = Xa[k4], xb = Xb[k4], xc = Xc[k4], xd = Xd[k4];
        #pragma unroll
        for (int kk = 0; kk < 4; ++kk) {
            float4 w = W4[(size_t)(k4 * 4 + kk) * 24 + c4q];
            float sa = ((const float*)&xa)[kk], sb = ((const float*)&xb)[kk];
            float sc = ((const float*)&xc)[kk], sd = ((const float*)&xd)[kk];
            accA.x += sa * w.x; accA.y += sa * w.y; accA.z += sa * w.z; accA.w += sa * w.w;
            accB.x += sb * w.x; accB.y += sb * w.y; accB.z += sb * w.z; accB.w += sb * w.w;
            accC.x += sc * w.x; accC.y += sc * w.y; accC.z += sc * w.z; accC.w += sc * w.w;
            accD.x += sd * w.x; accD.y += sd * w.y; accD.z += sd * w.z; accD.w += sd * w.w;
        }
    }
    float4 bb = ((const float4*)b)[c4q];
    float4* O = (float4*)out;
    float4 r;
    r.x = fmaxf(accA.x + bb.x, 0.f); r.y = fmaxf(accA.y + bb.y, 0.f);
    r.z = fmaxf(accA.z + bb.z, 0.f); r.w = fmaxf(accA.w + bb.w, 0.f);
    O[(size_t)n0 * 24 + c4q] = r;
    r.x = fmaxf(accB.x + bb.x, 0.f); r.y = fmaxf(accB.y + bb.y, 0.f);
    r.z = fmaxf(accB.z + bb.z, 0.f); r.w = fmaxf(accB.w + bb.w, 0.f);
    O[(size_t)(n0 + 1) * 24 + c4q] = r;
    r.x = fmaxf(accC.x + bb.x, 0.f); r.y = fmaxf(accC.y + bb.y, 0.f);
    r.z = fmaxf(accC.z + bb.z, 0.f); r.w = fmaxf(accC.w + bb.w, 0.f);
    O[(size_t)(n0 + 2) * 24 + c4q] = r;
    r.x = fmaxf(accD.x + bb.x, 0.f); r.y = fmaxf(accD.y + bb.y, 0.f);
    r.z = fmaxf(accD.z + bb.z, 0.f); r.w = fmaxf(accD.w + bb.w, 0.f);
    O[(size_t)(n0 + 3) * 24 + c4q] = r;
}

// ---------------- layers 1,2: GEMM (din=96) to fp16 h, WITH fused es/ed scores ----------
// 192-thread blocks = exactly 8 node-groups (32 nodes); per-thread partial dot
// acc·a_s[4ch] reduced via LDS float atomics; epilogue writes es/ed.
__global__ __launch_bounds__(192) void gemm_h16s_kernel(
    const float* __restrict__ x, const float* __restrict__ W,
    const float* __restrict__ a_s, const float* __restrict__ a_d,
    __half* __restrict__ h, float* __restrict__ es, float* __restrict__ ed) {
    __shared__ float s_ps[32], s_pd[32];
    if (threadIdx.x < 32) { s_ps[threadIdx.x] = 0.f; s_pd[threadIdx.x] = 0.f; }
    __syncthreads();

    int idx = blockIdx.x * 192 + threadIdx.x;
    bool active = idx < (N_NODES / 4) * 24;
    if (active) {
        int lg  = threadIdx.x / 24;          // local group 0..7
        int c4q = threadIdx.x - lg * 24;     // == idx % 24 (192 = 8*24)
        int n0 = (blockIdx.x * 8 + lg) * 4;
        const float4* X4 = (const float4*)x;
        const float4* W4 = (const float4*)W;
        const float4* Xa = X4 + (size_t)n0 * 24;
        const float4* Xb = Xa + 24;
        const float4* Xc = Xb + 24;
        const float4* Xd = Xc + 24;

        float4 accA = {0,0,0,0}, accB = {0,0,0,0}, accC = {0,0,0,0}, accD = {0,0,0,0};
        for (int k4 = 0; k4 < 24; ++k4) {
            float4 xa = Xa[k4], xb = Xb[k4], xc = Xc[k4], xd = Xd[k4];
            #pragma unroll
            for (int kk = 0; kk < 4; ++kk) {
                float4 w = W4[(size_t)(k4 * 4 + kk) * 24 + c4q];
                float sa = ((const float*)&xa)[kk], sb = ((const float*)&xb)[kk];
                float sc = ((const float*)&xc)[kk], sd = ((const float*)&xd)[kk];
                accA.x += sa * w.x; accA.y += sa * w.y; accA.z += sa * w.z; accA.w += sa * w.w;
                accB.x += sb * w.x; accB.y += sb * w.y; accB.z += sb * w.z; accB.w += sb * w.w;
                accC.x += sc * w.x; accC.y += sc * w.y; accC.z += sc * w.z; accC.w += sc * w.w;
                accD.x += sd * w.x; accD.y += sd * w.y; accD.z += sd * w.z; accD.w += sd * w.w;
            }
        }
        __half2* H2 = (__half2*)h;
        size_t rb = (size_t)n0 * 48 + c4q * 2;
        {
            __half2 p0 = __floats2half2_rn(accA.x, accA.y), p1 = __floats2half2_rn(accA.z, accA.w);
            uint2 st; st.x = *(unsigned*)&p0; st.y = *(unsigned*)&p1;
            *(uint2*)(H2 + rb) = st;
        }
        {
            __half2 p0 = __floats2half2_rn(accB.x, accB.y), p1 = __floats2half2_rn(accB.z, accB.w);
            uint2 st; st.x = *(unsigned*)&p0; st.y = *(unsigned*)&p1;
            *(uint2*)(H2 + rb + 48) = st;
        }
        {
            __half2 p0 = __floats2half2_rn(accC.x, accC.y), p1 = __floats2half2_rn(accC.z, accC.w);
            uint2 st; st.x = *(unsigned*)&p0; st.y = *(unsigned*)&p1;
            *(uint2*)(H2 + rb + 96) = st;
        }
        {
            __half2 p0 = __floats2half2_rn(accD.x, accD.y), p1 = __floats2half2_rn(accD.z, accD.w);
            uint2 st; st.x = *(unsigned*)&p0; st.y = *(unsigned*)&p1;
            *(uint2*)(H2 + rb + 144) = st;
        }
        // fused scores partials
        float4 sa4 = ((const float4*)a_s)[c4q];
        float4 sd4 = ((const float4*)a_d)[c4q];
        int nb = lg * 4;
        atomicAdd(&s_ps[nb + 0], accA.x * sa4.x + accA.y * sa4.y + accA.z * sa4.z + accA.w * sa4.w);
        atomicAdd(&s_ps[nb + 1], accB.x * sa4.x + accB.y * sa4.y + accB.z * sa4.z + accB.w * sa4.w);
        atomicAdd(&s_ps[nb + 2], accC.x * sa4.x + accC.y * sa4.y + accC.z * sa4.z + accC.w * sa4.w);
        atomicAdd(&s_ps[nb + 3], accD.x * sa4.x + accD.y * sa4.y + accD.z * sa4.z + accD.w * sa4.w);
        atomicAdd(&s_pd[nb + 0], accA.x * sd4.x + accA.y * sd4.y + accA.z * sd4.z + accA.w * sd4.w);
        atomicAdd(&s_pd[nb + 1], accB.x * sd4.x + accB.y * sd4.y + accB.z * sd4.z + accB.w * sd4.w);
        atomicAdd(&s_pd[nb + 2], accC.x * sd4.x + accC.y * sd4.y + accC.z * sd4.z + accC.w * sd4.w);
        atomicAdd(&s_pd[nb + 3], accD.x * sd4.x + accD.y * sd4.y + accD.z * sd4.z + accD.w * sd4.w);
    }
    __syncthreads();
    if (threadIdx.x < 32) {
        int node = blockIdx.x * 32 + threadIdx.x;
        if (node < N_NODES) {
            es[node] = s_ps[threadIdx.x];
            ed[node] = s_pd[threadIdx.x];
        }
    }
}

__global__ void final_proj_kernel(const float* __restrict__ x, const float* __restrict__ Wf,
                                  const float* __restrict__ asf, const float* __restrict__ adf,
                                  float* __restrict__ h, float* __restrict__ es,
                                  float* __restrict__ ed, int n) {
    int node = (int)((blockIdx.x * (long long)blockDim.x + threadIdx.x) >> 6);
    int lane = threadIdx.x & 63;
    if (node >= n) return;
    const float* xr = x + (long long)node * HID;
    float p = 0.f;
    for (int c = lane; c < HID; c += 64) p += xr[c] * Wf[c];
    #pragma unroll
    for (int o = 32; o; o >>= 1) p += __shfl_xor(p, o);
    if (lane == 0) {
        h[node] = p;
        es[node] = p * asf[0];
        ed[node] = p * adf[0];
    }
}

// ---------------- fused softmax + gather (96ch): 8 rows per unrolled iteration ----------
__global__ __launch_bounds__(256) void aggregate96_kernel(
    const unsigned* __restrict__ rs, const int* __restrict__ srcs,
    const float* __restrict__ es, const float* __restrict__ ed,
    const __half* __restrict__ h, const float* __restrict__ b,
    const float* __restrict__ res, float* __restrict__ out, int do_relu) {
    __shared__ uint2 sh[4][MAXD];
    int node = (int)((blockIdx.x * (long long)blockDim.x + threadIdx.x) >> 6);
    int lane = threadIdx.x & 63;
    int wv = threadIdx.x >> 6;
    int half = lane >> 5, lin = lane & 31;
    unsigned row = rs[node];
    int deg = (int)(rs[node + 1] - row);
    float edv = ed[node];

    float lsum = 0.f;
    float4 acc = {0.f, 0.f, 0.f, 0.f};
    const uint2* h4 = (const uint2*)h;    // row = 24 uint2 (96 halves)
    bool act = (lin < 24);

    for (int base = 0; base < deg; base += MAXD) {
        int cnt = min(MAXD, deg - base);
        for (int j = lane; j < cnt; j += 64) {
            int s = srcs[row + base + j];
            float v = es[s] + edv;
            v = v > 0.f ? v : NEG_SLOPE * v;
            float e = __expf(v);
            uint2 p; p.x = (unsigned)s; p.y = __float_as_uint(e);
            sh[wv][j] = p;   // same-wave RAW, ordered by lgkmcnt
            lsum += e;
        }
        int jb = 0;
        for (; jb + 8 <= cnt; jb += 8) {
            uint2 pa = sh[wv][jb + half];
            uint2 pb = sh[wv][jb + 2 + half];
            uint2 pc = sh[wv][jb + 4 + half];
            uint2 pd = sh[wv][jb + 6 + half];
            if (act) {
                uint2 qa = h4[(size_t)pa.x * 24 + lin];
                uint2 qb = h4[(size_t)pb.x * 24 + lin];
                uint2 qc = h4[(size_t)pc.x * 24 + lin];
                uint2 qd = h4[(size_t)pd.x * 24 + lin];
                float ea = __uint_as_float(pa.y), eb = __uint_as_float(pb.y);
                float ec = __uint_as_float(pc.y), ef = __uint_as_float(pd.y);
                float2 a0 = __half22float2(*(__half2*)&qa.x), a1 = __half22float2(*(__half2*)&qa.y);
                float2 b0 = __half22float2(*(__half2*)&qb.x), b1 = __half22float2(*(__half2*)&qb.y);
                float2 c0 = __half22float2(*(__half2*)&qc.x), c1 = __half22float2(*(__half2*)&qc.y);
                float2 d0 = __half22float2(*(__half2*)&qd.x), d1 = __half22float2(*(__half2*)&qd.y);
                acc.x += ea * a0.x + eb * b0.x + ec * c0.x + ef * d0.x;
                acc.y += ea * a0.y + eb * b0.y + ec * c0.y + ef * d0.y;
                acc.z += ea * a1.x + eb * b1.x + ec * c1.x + ef * d1.x;
                acc.w += ea * a1.y + eb * b1.y + ec * c1.y + ef * d1.y;
            }
        }
        for (; jb < cnt; jb += 2) {
            int r = jb + half;
            if (act && r < cnt) {
                uint2 p = sh[wv][r];
                float e = __uint_as_float(p.y);
                uint2 q = h4[(size_t)p.x * 24 + lin];
                float2 fa = __half22float2(*(__half2*)&q.x);
                float2 fb = __half22float2(*(__half2*)&q.y);
                acc.x += e * fa.x; acc.y += e * fa.y;
                acc.z += e * fb.x; acc.w += e * fb.y;
            }
        }
    }
    #pragma unroll
    for (int o = 32; o; o >>= 1) lsum += __shfl_xor(lsum, o);
    acc.x += __shfl_xor(acc.x, 32);
    acc.y += __shfl_xor(acc.y, 32);
    acc.z += __shfl_xor(acc.z, 32);
    acc.w += __shfl_xor(acc.w, 32);

    if (half == 0 && lin < 24) {
        float inv = 1.f / lsum;
        float4 bb = ((const float4*)b)[lin];
        float4 v;
        v.x = acc.x * inv + bb.x; v.y = acc.y * inv + bb.y;
        v.z = acc.z * inv + bb.z; v.w = acc.w * inv + bb.w;
        if (res) {
            float4 rr = ((const float4*)res)[(size_t)node * 24 + lin];
            v.x += rr.x; v.y += rr.y; v.z += rr.z; v.w += rr.w;
        }
        if (do_relu) {
            v.x = fmaxf(v.x, 0.f); v.y = fmaxf(v.y, 0.f);
            v.z = fmaxf(v.z, 0.f); v.w = fmaxf(v.w, 0.f);
        }
        ((float4*)out)[(size_t)node * 24 + lin] = v;
    }
}

// ---------------- dout=1 aggregate (final layer): single pass, no max ----------------
__global__ __launch_bounds__(256) void aggregate1_kernel(
    const unsigned* __restrict__ rs, const int* __restrict__ srcs,
    const float* __restrict__ es, const float* __restrict__ ed,
    const float* __restrict__ h, const float* __restrict__ b,
    float* __restrict__ out) {
    int node = (int)((blockIdx.x * (long long)blockDim.x + threadIdx.x) >> 6);
    int lane = threadIdx.x & 63;
    unsigned row = rs[node];
    int deg = (int)(rs[node + 1] - row);
    float edv = ed[node];

    float lsum = 0.f, acc = 0.f;
    for (int j = lane; j < deg; j += 64) {
        int s = srcs[row + j];
        float v = es[s] + edv;
        v = v > 0.f ? v : NEG_SLOPE * v;
        float ex = __expf(v);
        lsum += ex;
        acc += ex * h[s];
    }
    #pragma unroll
    for (int o = 32; o; o >>= 1) {
        lsum += __shfl_xor(lsum, o);
        acc  += __shfl_xor(acc, o);
    }
    if (lane == 0) out[node] = acc / lsum + b[0];
}

// ---------------- host-side orchestration ----------------

extern "C" void kernel_launch(void* const* d_in, const int* in_sizes, int n_in,
                              void* d_out, int out_size, void* d_ws, size_t ws_size,
                              hipStream_t stream) {
    const float* x  = (const float*)d_in[0];
    const int*   ei = (const int*)d_in[1];
    const float* W0 = (const float*)d_in[3];
    const float* as0 = (const float*)d_in[4];
    const float* ad0 = (const float*)d_in[5];
    const float* b0 = (const float*)d_in[6];
    const float* W1 = (const float*)d_in[7];
    const float* as1 = (const float*)d_in[8];
    const float* ad1 = (const float*)d_in[9];
    const float* b1 = (const float*)d_in[10];
    const float* W2 = (const float*)d_in[11];
    const float* as2 = (const float*)d_in[12];
    const float* ad2 = (const float*)d_in[13];
    const float* b2 = (const float*)d_in[14];
    const float* Wf = (const float*)d_in[15];
    const float* asf = (const float*)d_in[16];
    const float* adf = (const float*)d_in[17];
    const float* bf = (const float*)d_in[18];

    float* out = (float*)d_out;  // 50000 floats

    // workspace carve-up
    float* Hf = (float*)d_ws;                    // N*96 float slot: fp16 h / XH / DEG / final fp32 h
    __half* H16 = (__half*)Hf;
    float* FA = Hf + (long long)N_NODES * HID;   // N*96
    float* FB = FA + (long long)N_NODES * HID;   // N*96 (aliased as AGG during layer 0)
    float* ES = FB + (long long)N_NODES * HID;   // N
    float* ED = ES + N_NODES;                    // N
    unsigned* RS   = (unsigned*)(ED + N_NODES);  // N+1
    unsigned* WPTR = RS + (N_NODES + 1);         // N
    int* SRCS = (int*)(WPTR + N_NODES);          // E_TOT
    unsigned* DEG = (unsigned*)Hf;               // CSR temps aliased onto Hf (pre-prep)
    unsigned* BS  = DEG + N_NODES;
    __half* XH = (__half*)Hf;                    // N*32 fp16 x, aliased onto Hf after CSR
    float* AGG = FB;                             // N*32 fp32, FB free during layer 0

    // ---- CSR build (XCD-pinned windowed hist + fill) ----
    hipMemsetAsync(DEG, 0, (size_t)N_NODES * sizeof(unsigned), stream);
    const int nb_e = cdiv(E_TOT, 256);
    hist_win_kernel<<<nb_e * FILL_PASSES, 256, 0, stream>>>(ei, DEG);
    scan_block_kernel<<<N_SCAN_BLOCKS, SCAN_BS, 0, stream>>>(DEG, RS, BS, N_NODES);
    scan_fix_kernel<<<cdiv(N_NODES + 1, 256), 256, 0, stream>>>(RS, BS, WPTR, N_NODES);
    fill_win_kernel<<<nb_e * FILL_PASSES, 256, 0, stream>>>(ei, WPTR, SRCS);

    const int gemm_threads = (N_NODES / 4) * 24;   // 300000

    // ---- layer 0 (linearity): fused prep, gather fp16 x, then GEMM ----
    layer0_prep_kernel<<<(N_NODES * 32) / 256, 256, 0, stream>>>(x, W0, as0, ad0, XH, ES, ED);
    aggregate32_kernel<<<NODE_BLOCKS, 256, 0, stream>>>(RS, SRCS, ES, ED, XH, AGG);
    gemm32_kernel<<<cdiv(gemm_threads, 256), 256, 0, stream>>>(AGG, W0, b0, FA);

    // ---- layer 1: FA -> FB, residual FA, relu (gemm with fused scores) ----
    gemm_h16s_kernel<<<cdiv(gemm_threads, 192), 192, 0, stream>>>(FA, W1, as1, ad1, H16, ES, ED);
    aggregate96_kernel<<<NODE_BLOCKS, 256, 0, stream>>>(RS, SRCS, ES, ED, H16, b1, FA, FB, 1);

    // ---- layer 2: FB -> FA, residual FB, relu ----
    gemm_h16s_kernel<<<cdiv(gemm_threads, 192), 192, 0, stream>>>(FB, W2, as2, ad2, H16, ES, ED);
    aggregate96_kernel<<<NODE_BLOCKS, 256, 0, stream>>>(RS, SRCS, ES, ED, H16, b2, FB, FA, 1);

    // ---- final: FA -> out (dout=1), fp32 path ----
    final_proj_kernel<<<NODE_BLOCKS, 256, 0, stream>>>(FA, Wf, asf, adf, Hf, ES, ED, N_NODES);
    aggregate1_kernel<<<NODE_BLOCKS, 256, 0, stream>>>(RS, SRCS, ES, ED, Hf, bf, out);
}

// Round 10
// 354.635 us; speedup vs baseline: 1.7174x; 1.1370x over previous
//
#include <hip/hip_runtime.h>
#include <hip/hip_fp16.h>
#include <math.h>

#define N_NODES 50000
#define N_EDGES 800000
#define E_TOT   (N_EDGES + N_NODES)   // 850000, self-loops appended
#define IN_DIM  32
#define HID     96
#define NEG_SLOPE 0.2f
#define MAXD    128                   // LDS chunk per wave (per-chunk staging)
#define SCAN_BS 1024
#define N_SCAN_BLOCKS ((N_NODES + SCAN_BS - 1) / SCAN_BS)   // 49
#define FILL_PASSES 8
#define FILL_WIN (N_NODES / FILL_PASSES)   // 6250
#define NODE_BLOCKS (N_NODES / 4)          // 12500 blocks of 4 waves/nodes

typedef _Float16 half8v __attribute__((ext_vector_type(8)));
typedef float    float4v __attribute__((ext_vector_type(4)));

static inline int cdiv(long long a, int b) { return (int)((a + b - 1) / b); }

// ---------------- CSR build (counting sort by dst), once per launch ----------------

__global__ void hist_win_kernel(const int* __restrict__ ei, unsigned* __restrict__ deg) {
    int pass = blockIdx.x & 7;
    int eb   = blockIdx.x >> 3;
    int e = eb * 256 + threadIdx.x;
    if (e >= E_TOT) return;
    int d = (e < N_EDGES) ? ei[N_EDGES + e] : (e - N_EDGES);
    if ((unsigned)(d - pass * FILL_WIN) >= (unsigned)FILL_WIN) return;
    atomicAdd(deg + d, 1u);
}

__global__ void scan_block_kernel(const unsigned* __restrict__ deg, unsigned* __restrict__ rs,
                                  unsigned* __restrict__ bsums, int n) {
    __shared__ unsigned buf[SCAN_BS];
    int i = blockIdx.x * SCAN_BS + threadIdx.x;
    unsigned v = (i < n) ? deg[i] : 0u;
    buf[threadIdx.x] = v;
    __syncthreads();
    for (int o = 1; o < SCAN_BS; o <<= 1) {
        unsigned t = (threadIdx.x >= (unsigned)o) ? buf[threadIdx.x - o] : 0u;
        __syncthreads();
        buf[threadIdx.x] += t;
        __syncthreads();
    }
    if (i < n) rs[i] = buf[threadIdx.x] - v;
    if (threadIdx.x == SCAN_BS - 1) bsums[blockIdx.x] = buf[SCAN_BS - 1];
}

__global__ void scan_fix_kernel(unsigned* __restrict__ rs, const unsigned* __restrict__ bsums,
                                unsigned* __restrict__ wptr, int n) {
    __shared__ unsigned s_off;
    int k = blockIdx.x >> 2;
    if (threadIdx.x < 64) {
        unsigned v = ((int)threadIdx.x < k) ? bsums[threadIdx.x] : 0u;
        #pragma unroll
        for (int o = 32; o; o >>= 1) v += __shfl_xor(v, o);
        if (threadIdx.x == 0) s_off = v;
    }
    __syncthreads();
    unsigned off = s_off;
    int i = blockIdx.x * 256 + threadIdx.x;
    if (i < n) {
        unsigned r = rs[i] + off;
        rs[i] = r;
        wptr[i] = r;
    }
    if (i == n) rs[n] = E_TOT;
}

__global__ void fill_win_kernel(const int* __restrict__ ei, unsigned* __restrict__ wptr,
                                int* __restrict__ srcs) {
    int pass = blockIdx.x & 7;          // XCD-pinned pass (round-robin block->XCD)
    int eb   = blockIdx.x >> 3;
    int e = eb * 256 + threadIdx.x;
    if (e >= E_TOT) return;
    int lo = pass * FILL_WIN;
    int d = (e < N_EDGES) ? ei[N_EDGES + e] : (e - N_EDGES);
    if ((unsigned)(d - lo) >= (unsigned)FILL_WIN) return;
    int s = (e < N_EDGES) ? ei[e] : d;
    unsigned pos = atomicAdd(wptr + d, 1u);
    srcs[pos] = s;
}

// ---------------- weight prep: WT[n][k] = (half)W[k][n] for W1, W2 ----------------
__global__ void wtprep_kernel(const float* __restrict__ W1, const float* __restrict__ W2,
                              __half* __restrict__ WT1, __half* __restrict__ WT2) {
    int i = blockIdx.x * 256 + threadIdx.x;
    if (i >= HID * HID) return;
    int n = i / HID, k = i - n * HID;
    WT1[i] = __float2half(W1[k * HID + n]);
    WT2[i] = __float2half(W2[k * HID + n]);
}

// ---------------- layer-0 fused prep: uproj + scores0 + xcast in one kernel -------------
__global__ __launch_bounds__(256) void layer0_prep_kernel(
    const float* __restrict__ x, const float* __restrict__ W0,
    const float* __restrict__ as0, const float* __restrict__ ad0,
    __half* __restrict__ xh, float* __restrict__ es, float* __restrict__ ed) {
    __shared__ float s_us[32], s_ud[32];
    if (threadIdx.x < 64) {
        int k = threadIdx.x & 31;
        int sel = threadIdx.x >> 5;
        const float* a = sel ? ad0 : as0;
        float acc = 0.f;
        #pragma unroll 8
        for (int c = 0; c < HID; ++c) acc += W0[k * HID + c] * a[c];
        if (sel) s_ud[k] = acc; else s_us[k] = acc;
    }
    __syncthreads();
    int idx = blockIdx.x * 256 + threadIdx.x;   // grid = N*32 threads exactly
    int node = idx >> 5;
    int k = threadIdx.x & 31;
    float xv = x[(size_t)node * 32 + k];
    float xnb = __shfl_xor(xv, 1);
    if ((k & 1) == 0) {
        __half2 h2v = __floats2half2_rn(xv, xnb);
        ((__half2*)xh)[((size_t)node * 32 + k) >> 1] = h2v;
    }
    float ps = xv * s_us[k], pd = xv * s_ud[k];
    #pragma unroll
    for (int o = 16; o; o >>= 1) {
        ps += __shfl_xor(ps, o);
        pd += __shfl_xor(pd, o);
    }
    if (k == 0) { es[node] = ps; ed[node] = pd; }
}

// aggregate 32-dim fp16 x: agg[n,32] = softmax-weighted sum of x[src].
__global__ __launch_bounds__(256) void aggregate32_kernel(
    const unsigned* __restrict__ rs, const int* __restrict__ srcs,
    const float* __restrict__ es, const float* __restrict__ ed,
    const __half* __restrict__ xh, float* __restrict__ agg) {
    __shared__ uint2 sh[4][MAXD];
    int node = (int)((blockIdx.x * (long long)blockDim.x + threadIdx.x) >> 6);
    int lane = threadIdx.x & 63;
    int wv = threadIdx.x >> 6;
    int grp = lane >> 3, lin = lane & 7;
    unsigned row = rs[node];
    int deg = (int)(rs[node + 1] - row);
    float edv = ed[node];

    float lsum = 0.f;
    float4 acc = {0.f, 0.f, 0.f, 0.f};
    const uint2* x2 = (const uint2*)xh;   // row = 8 uint2

    for (int base = 0; base < deg; base += MAXD) {
        int cnt = min(MAXD, deg - base);
        for (int j = lane; j < cnt; j += 64) {
            int s = srcs[row + base + j];
            float v = es[s] + edv;
            v = v > 0.f ? v : NEG_SLOPE * v;
            float e = __expf(v);
            uint2 p; p.x = (unsigned)s; p.y = __float_as_uint(e);
            sh[wv][j] = p;
            lsum += e;
        }
        int jb = 0;
        for (; jb + 16 <= cnt; jb += 16) {
            uint2 pa = sh[wv][jb + grp];
            uint2 pb = sh[wv][jb + 8 + grp];
            uint2 qa = x2[(size_t)pa.x * 8 + lin];
            uint2 qb = x2[(size_t)pb.x * 8 + lin];
            float ea = __uint_as_float(pa.y), eb = __uint_as_float(pb.y);
            float2 fa0 = __half22float2(*(__half2*)&qa.x);
            float2 fa1 = __half22float2(*(__half2*)&qa.y);
            float2 fb0 = __half22float2(*(__half2*)&qb.x);
            float2 fb1 = __half22float2(*(__half2*)&qb.y);
            acc.x += ea * fa0.x + eb * fb0.x; acc.y += ea * fa0.y + eb * fb0.y;
            acc.z += ea * fa1.x + eb * fb1.x; acc.w += ea * fa1.y + eb * fb1.y;
        }
        for (; jb < cnt; jb += 8) {
            int r = jb + grp;
            if (r < cnt) {
                uint2 p = sh[wv][r];
                float e = __uint_as_float(p.y);
                uint2 q = x2[(size_t)p.x * 8 + lin];
                float2 fa = __half22float2(*(__half2*)&q.x);
                float2 fb = __half22float2(*(__half2*)&q.y);
                acc.x += e * fa.x; acc.y += e * fa.y;
                acc.z += e * fb.x; acc.w += e * fb.y;
            }
        }
    }
    #pragma unroll
    for (int o = 32; o; o >>= 1) lsum += __shfl_xor(lsum, o);
    #pragma unroll
    for (int o = 8; o <= 32; o <<= 1) {
        acc.x += __shfl_xor(acc.x, o);
        acc.y += __shfl_xor(acc.y, o);
        acc.z += __shfl_xor(acc.z, o);
        acc.w += __shfl_xor(acc.w, o);
    }
    if (grp == 0) {
        float inv = 1.f / lsum;
        float4 o4; o4.x = acc.x * inv; o4.y = acc.y * inv; o4.z = acc.z * inv; o4.w = acc.w * inv;
        ((float4*)agg)[(size_t)node * 8 + lin] = o4;
    }
}

// out = relu(agg @ W0 + b0), fp32 output + fp16 copy (layer-0 epilogue GEMM, din=32)
__global__ void gemm32_kernel(const float* __restrict__ agg, const float* __restrict__ W,
                              const float* __restrict__ b, float* __restrict__ out,
                              __half* __restrict__ out16) {
    int idx = blockIdx.x * blockDim.x + threadIdx.x;   // (n/4)*24 threads
    if (idx >= (N_NODES / 4) * 24) return;
    int g   = idx / 24;
    int c4q = idx - g * 24;
    int n0 = g * 4;
    const float4* Xa = (const float4*)agg + (size_t)n0 * 8;
    const float4* Xb = Xa + 8;
    const float4* Xc = Xb + 8;
    const float4* Xd = Xc + 8;
    const float4* W4 = (const float4*)W;   // row stride 24 float4

    float4 accA = {0,0,0,0}, accB = {0,0,0,0}, accC = {0,0,0,0}, accD = {0,0,0,0};
    for (int k4 = 0; k4 < 8; ++k4) {
        float4 xa = Xa[k4], xb = Xb[k4], xc = Xc[k4], xd = Xd[k4];
        #pragma unroll
        for (int kk = 0; kk < 4; ++kk) {
            float4 w = W4[(size_t)(k4 * 4 + kk) * 24 + c4q];
            float sa = ((const float*)&xa)[kk], sb = ((const float*)&xb)[kk];
            float sc = ((const float*)&xc)[kk], sd = ((const float*)&xd)[kk];
            accA.x += sa * w.x; accA.y += sa * w.y; accA.z += sa * w.z; accA.w += sa * w.w;
            accB.x += sb * w.x; accB.y += sb * w.y; accB.z += sb * w.z; accB.w += sb * w.w;
            accC.x += sc * w.x; accC.y += sc * w.y; accC.z += sc * w.z; accC.w += sc * w.w;
            accD.x += sd * w.x; accD.y += sd * w.y; accD.z += sd * w.z; accD.w += sd * w.w;
        }
    }
    float4 bb = ((const float4*)b)[c4q];
    float4* O = (float4*)out;
    uint2* O16 = (uint2*)out16;
    float4 r;
    #pragma unroll
    for (int nn = 0; nn < 4; ++nn) {
        float4 a = (nn == 0) ? accA : (nn == 1) ? accB : (nn == 2) ? accC : accD;
        r.x = fmaxf(a.x + bb.x, 0.f); r.y = fmaxf(a.y + bb.y, 0.f);
        r.z = fmaxf(a.z + bb.z, 0.f); r.w = fmaxf(a.w + bb.w, 0.f);
        O[(size_t)(n0 + nn) * 24 + c4q] = r;
        __half2 q0 = __floats2half2_rn(r.x, r.y), q1 = __floats2half2_rn(r.z, r.w);
        uint2 st; st.x = *(unsigned*)&q0; st.y = *(unsigned*)&q1;
        O16[(size_t)(n0 + nn) * 24 + c4q] = st;
    }
}

// ---------------- layers 1,2: MFMA GEMM (fp16 in, fp16 h out) with fused scores ---------
// One wave per 16-node M-tile. A[m=lane&15][k=quad*8+j] from row-major x16;
// B[n=lane&15][k=quad*8+j] from transposed WT; C/D: col=lane&15, row=quad*4+reg.
__global__ __launch_bounds__(256) void mfma_gemm96_kernel(
    const __half* __restrict__ x16, const __half* __restrict__ wt,
    const float* __restrict__ a_s, const float* __restrict__ a_d,
    __half* __restrict__ h, float* __restrict__ es, float* __restrict__ ed) {
    int wid = (int)((blockIdx.x * 256 + threadIdx.x) >> 6);
    if (wid >= N_NODES / 16) return;    // 3125 M-tiles
    int lane = threadIdx.x & 63;
    int col = lane & 15, quad = lane >> 4;
    int m0 = wid * 16;
    const __half* arow = x16 + (size_t)(m0 + col) * 96 + quad * 8;
    const __half* brow = wt + (size_t)col * 96 + quad * 8;

    float4v acc[6];
    #pragma unroll
    for (int t = 0; t < 6; ++t) acc[t] = (float4v){0.f, 0.f, 0.f, 0.f};

    #pragma unroll
    for (int ks = 0; ks < 3; ++ks) {
        half8v afrag = *(const half8v*)(arow + ks * 32);
        #pragma unroll
        for (int t = 0; t < 6; ++t) {
            half8v bfrag = *(const half8v*)(brow + (size_t)t * 16 * 96 + ks * 32);
            acc[t] = __builtin_amdgcn_mfma_f32_16x16x32_f16(afrag, bfrag, acc[t], 0, 0, 0);
        }
    }

    // epilogue: h fp16 stores + fused es/ed (from fp32 accumulators)
    float ps0 = 0.f, ps1 = 0.f, ps2 = 0.f, ps3 = 0.f;
    float pd0 = 0.f, pd1 = 0.f, pd2 = 0.f, pd3 = 0.f;
    #pragma unroll
    for (int t = 0; t < 6; ++t) {
        int ch = t * 16 + col;
        float sa = a_s[ch], sd = a_d[ch];
        float v0 = acc[t][0], v1 = acc[t][1], v2 = acc[t][2], v3 = acc[t][3];
        size_t rbase = (size_t)(m0 + quad * 4) * 96 + ch;
        h[rbase]       = __float2half(v0);
        h[rbase + 96]  = __float2half(v1);
        h[rbase + 192] = __float2half(v2);
        h[rbase + 288] = __float2half(v3);
        ps0 += v0 * sa; ps1 += v1 * sa; ps2 += v2 * sa; ps3 += v3 * sa;
        pd0 += v0 * sd; pd1 += v1 * sd; pd2 += v2 * sd; pd3 += v3 * sd;
    }
    #pragma unroll
    for (int o = 1; o < 16; o <<= 1) {
        ps0 += __shfl_xor(ps0, o); ps1 += __shfl_xor(ps1, o);
        ps2 += __shfl_xor(ps2, o); ps3 += __shfl_xor(ps3, o);
        pd0 += __shfl_xor(pd0, o); pd1 += __shfl_xor(pd1, o);
        pd2 += __shfl_xor(pd2, o); pd3 += __shfl_xor(pd3, o);
    }
    if (col == 0) {
        int nb = m0 + quad * 4;
        es[nb] = ps0; es[nb + 1] = ps1; es[nb + 2] = ps2; es[nb + 3] = ps3;
        ed[nb] = pd0; ed[nb + 1] = pd1; ed[nb + 2] = pd2; ed[nb + 3] = pd3;
    }
}

__global__ void final_proj_kernel(const float* __restrict__ x, const float* __restrict__ Wf,
                                  const float* __restrict__ asf, const float* __restrict__ adf,
                                  float* __restrict__ h, float* __restrict__ es,
                                  float* __restrict__ ed, int n) {
    int node = (int)((blockIdx.x * (long long)blockDim.x + threadIdx.x) >> 6);
    int lane = threadIdx.x & 63;
    if (node >= n) return;
    const float* xr = x + (long long)node * HID;
    float p = 0.f;
    for (int c = lane; c < HID; c += 64) p += xr[c] * Wf[c];
    #pragma unroll
    for (int o = 32; o; o >>= 1) p += __shfl_xor(p, o);
    if (lane == 0) {
        h[node] = p;
        es[node] = p * asf[0];
        ed[node] = p * adf[0];
    }
}

// ---------------- fused softmax + gather (96ch): 8 rows per unrolled iteration ----------
__global__ __launch_bounds__(256) void aggregate96_kernel(
    const unsigned* __restrict__ rs, const int* __restrict__ srcs,
    const float* __restrict__ es, const float* __restrict__ ed,
    const __half* __restrict__ h, const float* __restrict__ b,
    const float* __restrict__ res, float* __restrict__ out,
    __half* __restrict__ out16, int do_relu) {
    __shared__ uint2 sh[4][MAXD];
    int node = (int)((blockIdx.x * (long long)blockDim.x + threadIdx.x) >> 6);
    int lane = threadIdx.x & 63;
    int wv = threadIdx.x >> 6;
    int half_ = lane >> 5, lin = lane & 31;
    unsigned row = rs[node];
    int deg = (int)(rs[node + 1] - row);
    float edv = ed[node];

    float lsum = 0.f;
    float4 acc = {0.f, 0.f, 0.f, 0.f};
    const uint2* h4 = (const uint2*)h;    // row = 24 uint2 (96 halves)
    bool act = (lin < 24);

    for (int base = 0; base < deg; base += MAXD) {
        int cnt = min(MAXD, deg - base);
        for (int j = lane; j < cnt; j += 64) {
            int s = srcs[row + base + j];
            float v = es[s] + edv;
            v = v > 0.f ? v : NEG_SLOPE * v;
            float e = __expf(v);
            uint2 p; p.x = (unsigned)s; p.y = __float_as_uint(e);
            sh[wv][j] = p;   // same-wave RAW, ordered by lgkmcnt
            lsum += e;
        }
        int jb = 0;
        for (; jb + 8 <= cnt; jb += 8) {
            uint2 pa = sh[wv][jb + half_];
            uint2 pb = sh[wv][jb + 2 + half_];
            uint2 pc = sh[wv][jb + 4 + half_];
            uint2 pd = sh[wv][jb + 6 + half_];
            if (act) {
                uint2 qa = h4[(size_t)pa.x * 24 + lin];
                uint2 qb = h4[(size_t)pb.x * 24 + lin];
                uint2 qc = h4[(size_t)pc.x * 24 + lin];
                uint2 qd = h4[(size_t)pd.x * 24 + lin];
                float ea = __uint_as_float(pa.y), eb = __uint_as_float(pb.y);
                float ec = __uint_as_float(pc.y), ef = __uint_as_float(pd.y);
                float2 a0 = __half22float2(*(__half2*)&qa.x), a1 = __half22float2(*(__half2*)&qa.y);
                float2 b0 = __half22float2(*(__half2*)&qb.x), b1 = __half22float2(*(__half2*)&qb.y);
                float2 c0 = __half22float2(*(__half2*)&qc.x), c1 = __half22float2(*(__half2*)&qc.y);
                float2 d0 = __half22float2(*(__half2*)&qd.x), d1 = __half22float2(*(__half2*)&qd.y);
                acc.x += ea * a0.x + eb * b0.x + ec * c0.x + ef * d0.x;
                acc.y += ea * a0.y + eb * b0.y + ec * c0.y + ef * d0.y;
                acc.z += ea * a1.x + eb * b1.x + ec * c1.x + ef * d1.x;
                acc.w += ea * a1.y + eb * b1.y + ec * c1.y + ef * d1.y;
            }
        }
        for (; jb < cnt; jb += 2) {
            int r = jb + half_;
            if (act && r < cnt) {
                uint2 p = sh[wv][r];
                float e = __uint_as_float(p.y);
                uint2 q = h4[(size_t)p.x * 24 + lin];
                float2 fa = __half22float2(*(__half2*)&q.x);
                float2 fb = __half22float2(*(__half2*)&q.y);
                acc.x += e * fa.x; acc.y += e * fa.y;
                acc.z += e * fb.x; acc.w += e * fb.y;
            }
        }
    }
    #pragma unroll
    for (int o = 32; o; o >>= 1) lsum += __shfl_xor(lsum, o);
    acc.x += __shfl_xor(acc.x, 32);
    acc.y += __shfl_xor(acc.y, 32);
    acc.z += __shfl_xor(acc.z, 32);
    acc.w += __shfl_xor(acc.w, 32);

    if (half_ == 0 && lin < 24) {
        float inv = 1.f / lsum;
        float4 bb = ((const float4*)b)[lin];
        float4 v;
        v.x = acc.x * inv + bb.x; v.y = acc.y * inv + bb.y;
        v.z = acc.z * inv + bb.z; v.w = acc.w * inv + bb.w;
        if (res) {
            float4 rr = ((const float4*)res)[(size_t)node * 24 + lin];
            v.x += rr.x; v.y += rr.y; v.z += rr.z; v.w += rr.w;
        }
        if (do_relu) {
            v.x = fmaxf(v.x, 0.f); v.y = fmaxf(v.y, 0.f);
            v.z = fmaxf(v.z, 0.f); v.w = fmaxf(v.w, 0.f);
        }
        ((float4*)out)[(size_t)node * 24 + lin] = v;
        if (out16) {
            __half2 q0 = __floats2half2_rn(v.x, v.y), q1 = __floats2half2_rn(v.z, v.w);
            uint2 st; st.x = *(unsigned*)&q0; st.y = *(unsigned*)&q1;
            ((uint2*)out16)[(size_t)node * 24 + lin] = st;
        }
    }
}

// ---------------- dout=1 aggregate (final layer): single pass, no max ----------------
__global__ __launch_bounds__(256) void aggregate1_kernel(
    const unsigned* __restrict__ rs, const int* __restrict__ srcs,
    const float* __restrict__ es, const float* __restrict__ ed,
    const float* __restrict__ h, const float* __restrict__ b,
    float* __restrict__ out) {
    int node = (int)((blockIdx.x * (long long)blockDim.x + threadIdx.x) >> 6);
    int lane = threadIdx.x & 63;
    unsigned row = rs[node];
    int deg = (int)(rs[node + 1] - row);
    float edv = ed[node];

    float lsum = 0.f, acc = 0.f;
    for (int j = lane; j < deg; j += 64) {
        int s = srcs[row + j];
        float v = es[s] + edv;
        v = v > 0.f ? v : NEG_SLOPE * v;
        float ex = __expf(v);
        lsum += ex;
        acc += ex * h[s];
    }
    #pragma unroll
    for (int o = 32; o; o >>= 1) {
        lsum += __shfl_xor(lsum, o);
        acc  += __shfl_xor(acc, o);
    }
    if (lane == 0) out[node] = acc / lsum + b[0];
}

// ---------------- host-side orchestration ----------------

extern "C" void kernel_launch(void* const* d_in, const int* in_sizes, int n_in,
                              void* d_out, int out_size, void* d_ws, size_t ws_size,
                              hipStream_t stream) {
    const float* x  = (const float*)d_in[0];
    const int*   ei = (const int*)d_in[1];
    const float* W0 = (const float*)d_in[3];
    const float* as0 = (const float*)d_in[4];
    const float* ad0 = (const float*)d_in[5];
    const float* b0 = (const float*)d_in[6];
    const float* W1 = (const float*)d_in[7];
    const float* as1 = (const float*)d_in[8];
    const float* ad1 = (const float*)d_in[9];
    const float* b1 = (const float*)d_in[10];
    const float* W2 = (const float*)d_in[11];
    const float* as2 = (const float*)d_in[12];
    const float* ad2 = (const float*)d_in[13];
    const float* b2 = (const float*)d_in[14];
    const float* Wf = (const float*)d_in[15];
    const float* asf = (const float*)d_in[16];
    const float* adf = (const float*)d_in[17];
    const float* bf = (const float*)d_in[18];

    float* out = (float*)d_out;  // 50000 floats

    // workspace carve-up
    float* Hf = (float*)d_ws;                    // N*96 float slot: fp16 h / XH / DEG / final fp32 h
    __half* H16 = (__half*)Hf;
    float* FA = Hf + (long long)N_NODES * HID;   // N*96
    float* FB = FA + (long long)N_NODES * HID;   // N*96 (aliased as AGG during layer 0)
    float* ES = FB + (long long)N_NODES * HID;   // N
    float* ED = ES + N_NODES;                    // N
    unsigned* RS   = (unsigned*)(ED + N_NODES);  // N+1
    unsigned* WPTR = RS + (N_NODES + 1);         // N
    int* SRCS = (int*)(WPTR + N_NODES);          // E_TOT
    __half* X16A = (__half*)(SRCS + E_TOT + 2);  // N*96 halves (fp16 features for MFMA A)
    __half* X16B = X16A + (size_t)N_NODES * HID; // N*96 halves
    __half* WT1 = X16B + (size_t)N_NODES * HID;  // 96*96 halves
    __half* WT2 = WT1 + HID * HID;               // 96*96 halves
    unsigned* DEG = (unsigned*)Hf;               // CSR temps aliased onto Hf (pre-prep)
    unsigned* BS  = DEG + N_NODES;
    __half* XH = (__half*)Hf;                    // N*32 fp16 x, aliased onto Hf after CSR
    float* AGG = FB;                             // N*32 fp32, FB free during layer 0

    // ---- CSR build (XCD-pinned windowed hist + fill) ----
    hipMemsetAsync(DEG, 0, (size_t)N_NODES * sizeof(unsigned), stream);
    const int nb_e = cdiv(E_TOT, 256);
    hist_win_kernel<<<nb_e * FILL_PASSES, 256, 0, stream>>>(ei, DEG);
    scan_block_kernel<<<N_SCAN_BLOCKS, SCAN_BS, 0, stream>>>(DEG, RS, BS, N_NODES);
    scan_fix_kernel<<<cdiv(N_NODES + 1, 256), 256, 0, stream>>>(RS, BS, WPTR, N_NODES);
    fill_win_kernel<<<nb_e * FILL_PASSES, 256, 0, stream>>>(ei, WPTR, SRCS);
    wtprep_kernel<<<cdiv(HID * HID, 256), 256, 0, stream>>>(W1, W2, WT1, WT2);

    const int gemm_threads = (N_NODES / 4) * 24;   // 300000
    const int mfma_blocks = cdiv(N_NODES / 16, 4); // 3125 waves -> 782 blocks

    // ---- layer 0 (linearity): fused prep, gather fp16 x, then GEMM ----
    layer0_prep_kernel<<<(N_NODES * 32) / 256, 256, 0, stream>>>(x, W0, as0, ad0, XH, ES, ED);
    aggregate32_kernel<<<NODE_BLOCKS, 256, 0, stream>>>(RS, SRCS, ES, ED, XH, AGG);
    gemm32_kernel<<<cdiv(gemm_threads, 256), 256, 0, stream>>>(AGG, W0, b0, FA, X16A);

    // ---- layer 1: FA -> FB, residual FA, relu (MFMA gemm + fused scores) ----
    mfma_gemm96_kernel<<<mfma_blocks, 256, 0, stream>>>(X16A, WT1, as1, ad1, H16, ES, ED);
    aggregate96_kernel<<<NODE_BLOCKS, 256, 0, stream>>>(RS, SRCS, ES, ED, H16, b1, FA, FB, X16B, 1);

    // ---- layer 2: FB -> FA, residual FB, relu ----
    mfma_gemm96_kernel<<<mfma_blocks, 256, 0, stream>>>(X16B, WT2, as2, ad2, H16, ES, ED);
    aggregate96_kernel<<<NODE_BLOCKS, 256, 0, stream>>>(RS, SRCS, ES, ED, H16, b2, FB, FA, nullptr, 1);

    // ---- final: FA -> out (dout=1), fp32 path ----
    final_proj_kernel<<<NODE_BLOCKS, 256, 0, stream>>>(FA, Wf, asf, adf, Hf, ES, ED, N_NODES);
    aggregate1_kernel<<<NODE_BLOCKS, 256, 0, stream>>>(RS, SRCS, ES, ED, Hf, bf, out);
}